// Round 2
// baseline (4744.131 us; speedup 1.0000x reference)
//
#include <hip/hip_runtime.h>

typedef __attribute__((ext_vector_type(8))) short short8;
typedef __attribute__((ext_vector_type(4))) float f32x4;

#define DEV static __device__ __forceinline__

DEV unsigned short f2bf(float x) {
  unsigned u = __float_as_uint(x);
  return (unsigned short)((u + 0x7fffu + ((u >> 16) & 1u)) >> 16);
}
DEV float bf2f(unsigned short h) { return __uint_as_float(((unsigned)h) << 16); }

// ---------------- prep: stable descending argsort + int outputs ----------------
__global__ void k_prep(const int* __restrict__ cap_len, const int* __restrict__ captions,
                       int* __restrict__ sind, int* __restrict__ dlen, int* __restrict__ emb_rows,
                       float* __restrict__ out_caps, float* __restrict__ out_dlen,
                       float* __restrict__ out_sind) {
  __shared__ int lens[64];
  __shared__ int ssind[64];
  int i = threadIdx.x;
  lens[i] = cap_len[i];
  __syncthreads();
  int li = lens[i];
  int rank = 0;
  for (int j = 0; j < 64; ++j) {
    int lj = lens[j];
    rank += (lj > li || (lj == li && j < i)) ? 1 : 0;
  }
  ssind[rank] = i;
  __syncthreads();
  int b = i;
  int s = ssind[b];
  sind[b] = s;
  int dl = lens[s] - 1;
  dlen[b] = dl;
  out_dlen[b] = (float)dl;
  out_sind[b] = (float)s;
  for (int l = 0; l < 22; ++l) {
    int cv = captions[s * 22 + l];
    out_caps[b * 22 + l] = (float)cv;
    if (l < 21) emb_rows[l * 64 + b] = cv;
  }
}

// ---------------- gather sorted encoder rows -> bf16 ----------------
__global__ __launch_bounds__(256) void k_gather_enc(const float* __restrict__ enc,
                                                    const int* __restrict__ sind,
                                                    unsigned short* __restrict__ dst) {
  int bp = blockIdx.x;  // 0..12543
  int b = bp / 196, p = bp % 196;
  const float* src = enc + ((size_t)sind[b] * 196 + p) * 2048 + threadIdx.x * 8;
  float4 v0 = *(const float4*)src;
  float4 v1 = *(const float4*)(src + 4);
  uint4 o;
  o.x = f2bf(v0.x) | ((unsigned)f2bf(v0.y) << 16);
  o.y = f2bf(v0.z) | ((unsigned)f2bf(v0.w) << 16);
  o.z = f2bf(v1.x) | ((unsigned)f2bf(v1.y) << 16);
  o.w = f2bf(v1.z) | ((unsigned)f2bf(v1.w) << 16);
  *(uint4*)(dst + (size_t)bp * 2048 + threadIdx.x * 8) = o;
}

// ---------------- flat f32 -> bf16 ----------------
__global__ __launch_bounds__(256) void k_convert(const float* __restrict__ src,
                                                 unsigned short* __restrict__ dst, int n8) {
  int i = blockIdx.x * 256 + threadIdx.x;
  if (i >= n8) return;
  float4 v0 = *(const float4*)(src + (size_t)i * 8);
  float4 v1 = *(const float4*)(src + (size_t)i * 8 + 4);
  uint4 o;
  o.x = f2bf(v0.x) | ((unsigned)f2bf(v0.y) << 16);
  o.y = f2bf(v0.z) | ((unsigned)f2bf(v0.w) << 16);
  o.z = f2bf(v1.x) | ((unsigned)f2bf(v1.y) << 16);
  o.w = f2bf(v1.z) | ((unsigned)f2bf(v1.w) << 16);
  *(uint4*)(dst + (size_t)i * 8) = o;
}

// ---------------- transpose-convert: src f32 [Ks][N] -> dst bf16 [N][Ks] ----------------
__global__ __launch_bounds__(256) void k_tc(const float* __restrict__ src,
                                            unsigned short* __restrict__ dst, int Ks, int N) {
  __shared__ float tile[64][65];
  int n0 = blockIdx.x * 64, k0 = blockIdx.y * 64;
  int tx = threadIdx.x & 63, ty = threadIdx.x >> 6;
#pragma unroll
  for (int r = 0; r < 16; ++r) {
    int kr = r * 4 + ty;
    tile[kr][tx] = src[(size_t)(k0 + kr) * N + n0 + tx];
  }
  __syncthreads();
#pragma unroll
  for (int r = 0; r < 16; ++r) {
    int nr = r * 4 + ty;
    dst[(size_t)(n0 + nr) * Ks + k0 + tx] = f2bf(tile[tx][nr]);
  }
}

// ---------------- gather embedding rows -> bf16 A [1408][512] (zero pad) ----------------
__global__ __launch_bounds__(256) void k_gather_emb(const float* __restrict__ emb,
                                                    const int* __restrict__ rows,
                                                    unsigned short* __restrict__ dst) {
  int r = blockIdx.x;
  unsigned short* d = dst + (size_t)r * 512;
  int t = threadIdx.x;
  if (r >= 1344) { d[t] = 0; d[t + 256] = 0; return; }
  const float* s = emb + (size_t)rows[r] * 512;
  d[t] = f2bf(s[t]);
  d[t + 256] = f2bf(s[t + 256]);
}

// ---------------- mean over 196 pixels (from sorted bf16 enc) -> bf16 ----------------
__global__ __launch_bounds__(256) void k_meanb(const unsigned short* __restrict__ encb,
                                               unsigned short* __restrict__ meanb) {
  int b = blockIdx.x, e = blockIdx.y * 256 + threadIdx.x;
  const unsigned short* base = encb + (size_t)b * 196 * 2048 + e;
  float s = 0.f;
  for (int p = 0; p < 196; ++p) s += bf2f(base[(size_t)p * 2048]);
  meanb[(size_t)b * 2048 + e] = f2bf(s * (1.0f / 196.0f));
}

__global__ void k_biascat(const float* __restrict__ bh, const float* __restrict__ bc,
                          float* __restrict__ dst) {
  int i = blockIdx.x * 256 + threadIdx.x;  // grid 4
  dst[i] = (i < 512) ? bh[i] : bc[i - 512];
}

__global__ void k_h0b(const float* __restrict__ hc, unsigned short* __restrict__ hb) {
  int i = blockIdx.x * 256 + threadIdx.x;  // 32768
  int b = i >> 9, j = i & 511;
  hb[i] = f2bf(hc[b * 1024 + j]);
}

// ---------------- MFMA GEMM: C[M][N] = A[M][K] @ Bt[N][K]^T (+bias) ----------------
// 128x128 tile, BK=64, 4 waves (2x2 of 64x64), XOR-swizzled LDS.
__global__ __launch_bounds__(256) void k_gemm(const unsigned short* __restrict__ A,
                                              const unsigned short* __restrict__ Bt,
                                              const float* __restrict__ bias1,
                                              const float* __restrict__ bias2,
                                              float* __restrict__ Cf,
                                              unsigned short* __restrict__ Cb,
                                              const int* __restrict__ dlen,
                                              int M, int N, int K, int mode, int Mreal) {
  __shared__ unsigned short As[128 * 64];
  __shared__ unsigned short Bs[128 * 64];
  int t = threadIdx.x;
  int lane = t & 63, w = t >> 6;
  int wm = w >> 1, wn = w & 1;
  int m0 = blockIdx.x * 128, n0 = blockIdx.y * 128;
  f32x4 acc[4][4] = {};
  uint4 ra[4], rb[4];

#define LOADREGS(kc)                                                             \
  {                                                                              \
    _Pragma("unroll") for (int r = 0; r < 4; ++r) {                              \
      int idx = r * 256 + t;                                                     \
      int row = idx >> 3, ke = (idx & 7) * 8;                                    \
      ra[r] = *(const uint4*)(A + (size_t)(m0 + row) * K + (kc) + ke);           \
      rb[r] = *(const uint4*)(Bt + (size_t)(n0 + row) * K + (kc) + ke);          \
    }                                                                            \
  }

  LOADREGS(0);
  for (int kc = 0; kc < K; kc += 64) {
    __syncthreads();
#pragma unroll
    for (int r = 0; r < 4; ++r) {
      int idx = r * 256 + t;
      int row = idx >> 3, cb = (idx & 7) * 16;
      int sw = cb ^ ((row & 7) << 4);
      *(uint4*)((char*)As + row * 128 + sw) = ra[r];
      *(uint4*)((char*)Bs + row * 128 + sw) = rb[r];
    }
    __syncthreads();
    if (kc + 64 < K) LOADREGS(kc + 64);
#pragma unroll
    for (int ks = 0; ks < 2; ++ks) {
      short8 af[4], bf[4];
#pragma unroll
      for (int mi = 0; mi < 4; ++mi) {
        int row = wm * 64 + mi * 16 + (lane & 15);
        int kb = (ks * 64 + (lane >> 4) * 16) ^ ((row & 7) << 4);
        af[mi] = *(const short8*)((const char*)As + row * 128 + kb);
      }
#pragma unroll
      for (int ni = 0; ni < 4; ++ni) {
        int row = wn * 64 + ni * 16 + (lane & 15);
        int kb = (ks * 64 + (lane >> 4) * 16) ^ ((row & 7) << 4);
        bf[ni] = *(const short8*)((const char*)Bs + row * 128 + kb);
      }
#pragma unroll
      for (int mi = 0; mi < 4; ++mi)
#pragma unroll
        for (int ni = 0; ni < 4; ++ni)
          acc[mi][ni] = __builtin_amdgcn_mfma_f32_16x16x32_bf16(af[mi], bf[ni], acc[mi][ni], 0, 0, 0);
    }
  }
  int rbase = (lane >> 4) * 4;
#pragma unroll
  for (int mi = 0; mi < 4; ++mi) {
#pragma unroll
    for (int ni = 0; ni < 4; ++ni) {
      int n = n0 + wn * 64 + ni * 16 + (lane & 15);
      float badd = (bias1 ? bias1[n] : 0.f) + (bias2 ? bias2[n] : 0.f);
#pragma unroll
      for (int r = 0; r < 4; ++r) {
        int m = m0 + wm * 64 + mi * 16 + rbase + r;
        if (m >= Mreal) continue;
        float v = acc[mi][ni][r] + badd;
        if (mode == 0) {
          Cf[(size_t)m * N + n] = v;
        } else if (mode == 1) {
          Cb[(size_t)m * N + n] = f2bf(v);
        } else {
          int tt = m >> 6, bb = m & 63;
          Cf[(size_t)bb * 672000 + (size_t)tt * 32000 + n] = (tt < dlen[bb]) ? v : 0.f;
        }
      }
    }
  }
#undef LOADREGS
}

// ---------------- persistent 21-step decoder loop ----------------
struct GBar { unsigned cnt; unsigned gen; };

DEV void gbar(GBar* bar, unsigned mygen) {
  __syncthreads();
  if (threadIdx.x == 0) {
    __threadfence();
    unsigned old = __hip_atomic_fetch_add(&bar->cnt, 1u, __ATOMIC_ACQ_REL, __HIP_MEMORY_SCOPE_AGENT);
    if (old == 255u) {
      __hip_atomic_store(&bar->cnt, 0u, __ATOMIC_RELAXED, __HIP_MEMORY_SCOPE_AGENT);
      __hip_atomic_fetch_add(&bar->gen, 1u, __ATOMIC_RELEASE, __HIP_MEMORY_SCOPE_AGENT);
    } else {
      while (__hip_atomic_load(&bar->gen, __ATOMIC_RELAXED, __HIP_MEMORY_SCOPE_AGENT) == mygen) {
        __builtin_amdgcn_s_sleep(2);
      }
    }
    __threadfence();
  }
  __syncthreads();
}

__global__ __launch_bounds__(256, 1) void k_loop(
    const unsigned short* __restrict__ preatt, const unsigned short* __restrict__ encb,
    const unsigned short* __restrict__ WdB, const float* __restrict__ bd,
    const float* __restrict__ v_att, const float* __restrict__ Wbeta,
    const float* __restrict__ bbeta, const unsigned short* __restrict__ Wih2T,
    const unsigned short* __restrict__ WhhT, const float* __restrict__ ge,
    const int* __restrict__ dlen, float* __restrict__ hc, unsigned short* __restrict__ hb,
    unsigned short* __restrict__ zb, float* __restrict__ alphag,
    unsigned short* __restrict__ hall, GBar* bar) {
  __shared__ union {
    struct { float hld[512]; float datt[512]; float eld[200]; float red[256]; } att;
    struct { float lred[3][64][64]; int dl[64]; } p4;
    struct { float al[200]; } zp;
  } sm;
  int blk = blockIdx.x;
  int t = threadIdx.x;
  int lane = t & 63, w = t >> 6;
  unsigned gcount = 0;

  for (int s = 0; s < 21; ++s) {
    // ---- P2: attention (blocks 0..63, one per batch) ----
    if (blk < 64) {
      int b = blk;
      sm.att.hld[t] = hc[b * 1024 + t];
      sm.att.hld[t + 256] = hc[b * 1024 + 256 + t];
      __syncthreads();
      // d_att: 2 cols per thread, Wd bf16 [k][n]
      int j0 = t * 2;
      float a0 = bd[j0], a1 = bd[j0 + 1];
#pragma unroll 4
      for (int k = 0; k < 512; ++k) {
        float hv = sm.att.hld[k];
        unsigned wv = *(const unsigned*)(WdB + (size_t)k * 512 + j0);
        a0 += hv * bf2f((unsigned short)(wv & 0xffffu));
        a1 += hv * bf2f((unsigned short)(wv >> 16));
      }
      sm.att.datt[j0] = a0;
      sm.att.datt[j0 + 1] = a1;
      // gate = h @ W_beta + b_beta
      sm.att.red[t] = sm.att.hld[t] * Wbeta[t] + sm.att.hld[t + 256] * Wbeta[t + 256];
      __syncthreads();
      for (int st = 128; st > 0; st >>= 1) {
        if (t < st) sm.att.red[t] += sm.att.red[t + st];
        __syncthreads();
      }
      float gate = sm.att.red[0] + bbeta[0];
      __syncthreads();
      // e: wave per pixel, 8 elems/lane in registers
      float dv[8], vv[8];
#pragma unroll
      for (int j = 0; j < 8; ++j) {
        dv[j] = sm.att.datt[lane * 8 + j];
        vv[j] = v_att[lane * 8 + j];
      }
      for (int p = w; p < 196; p += 4) {
        short8 pv = *(const short8*)(preatt + ((size_t)b * 196 + p) * 512 + lane * 8);
        float acc = 0.f;
#pragma unroll
        for (int j = 0; j < 8; ++j) {
          float x = bf2f((unsigned short)pv[j]) + dv[j];
          acc += fmaxf(x, 0.f) * vv[j];
        }
#pragma unroll
        for (int off = 32; off > 0; off >>= 1) acc += __shfl_down(acc, off, 64);
        if (lane == 0) sm.att.eld[p] = acc;
      }
      __syncthreads();
      sm.att.red[t] = (t < 196) ? sm.att.eld[t] : -3.4e38f;
      __syncthreads();
      for (int st = 128; st > 0; st >>= 1) {
        if (t < st) sm.att.red[t] = fmaxf(sm.att.red[t], sm.att.red[t + st]);
        __syncthreads();
      }
      float mx = sm.att.red[0];
      __syncthreads();
      float ex = (t < 196) ? expf(sm.att.eld[t] - mx) : 0.f;
      sm.att.red[t] = ex;
      __syncthreads();
      for (int st = 128; st > 0; st >>= 1) {
        if (t < st) sm.att.red[t] += sm.att.red[t + st];
        __syncthreads();
      }
      float inv = gate / sm.att.red[0];
      if (t < 196) alphag[b * 196 + t] = ex * inv;  // gate folded in
    }
    gbar(bar, gcount); ++gcount;

    // ---- P3: z = alphag @ enc (all 256 blocks; b=blk>>2, chunk=blk&3) ----
    {
      int b = blk >> 2, ch = blk & 3;
      if (t < 196) sm.zp.al[t] = alphag[b * 196 + t];
      __syncthreads();
      int e0 = ch * 512 + t * 2;
      const unsigned short* base = encb + (size_t)b * 196 * 2048 + e0;
      float a0 = 0.f, a1 = 0.f;
#pragma unroll 4
      for (int p = 0; p < 196; ++p) {
        unsigned v = *(const unsigned*)(base + (size_t)p * 2048);
        float al = sm.zp.al[p];
        a0 += al * bf2f((unsigned short)(v & 0xffffu));
        a1 += al * bf2f((unsigned short)(v >> 16));
      }
      *(unsigned*)(zb + (size_t)b * 2048 + e0) =
          (unsigned)f2bf(a0) | ((unsigned)f2bf(a1) << 16);
    }
    gbar(bar, gcount); ++gcount;

    // ---- P4: gates = [zb|hb] @ [Wih2T|WhhT]^T, fused LSTM cell (blocks 0..31) ----
    if (blk < 32) {
      int c = blk;
      if (t < 64) sm.p4.dl[t] = dlen[t];
      f32x4 acc[4][4] = {};
      int mrow = lane & 15;
      int kq = lane >> 4;
      int nrow0 = c * 16 + (lane & 15);
      for (int ks = w; ks < 80; ks += 4) {
        short8 a[4], bfr[4];
        if (ks < 64) {
          int k = ks * 32 + kq * 8;
#pragma unroll
          for (int mi = 0; mi < 4; ++mi)
            a[mi] = *(const short8*)(zb + (size_t)(mi * 16 + mrow) * 2048 + k);
#pragma unroll
          for (int ni = 0; ni < 4; ++ni)
            bfr[ni] = *(const short8*)(Wih2T + (size_t)(ni * 512 + nrow0) * 2048 + k);
        } else {
          int k = (ks - 64) * 32 + kq * 8;
#pragma unroll
          for (int mi = 0; mi < 4; ++mi)
            a[mi] = *(const short8*)(hb + (size_t)(mi * 16 + mrow) * 512 + k);
#pragma unroll
          for (int ni = 0; ni < 4; ++ni)
            bfr[ni] = *(const short8*)(WhhT + (size_t)(ni * 512 + nrow0) * 512 + k);
        }
#pragma unroll
        for (int mi = 0; mi < 4; ++mi)
#pragma unroll
          for (int ni = 0; ni < 4; ++ni)
            acc[mi][ni] = __builtin_amdgcn_mfma_f32_16x16x32_bf16(a[mi], bfr[ni], acc[mi][ni], 0, 0, 0);
      }
      if (w > 0) {
#pragma unroll
        for (int mi = 0; mi < 4; ++mi)
#pragma unroll
          for (int ni = 0; ni < 4; ++ni)
            *(f32x4*)&sm.p4.lred[w - 1][lane][(mi * 4 + ni) * 4] = acc[mi][ni];
      }
      __syncthreads();
      if (w == 0) {
#pragma unroll
        for (int wv = 0; wv < 3; ++wv)
#pragma unroll
          for (int mi = 0; mi < 4; ++mi)
#pragma unroll
            for (int ni = 0; ni < 4; ++ni)
              acc[mi][ni] += *(const f32x4*)&sm.p4.lred[wv][lane][(mi * 4 + ni) * 4];
        int j = c * 16 + (lane & 15);
#pragma unroll
        for (int mi = 0; mi < 4; ++mi) {
#pragma unroll
          for (int r = 0; r < 4; ++r) {
            int b = mi * 16 + (lane >> 4) * 4 + r;
            const float* gep = ge + ((size_t)(s * 64 + b)) * 2048;
            float gi = acc[mi][0][r] + gep[j];
            float gf = acc[mi][1][r] + gep[512 + j];
            float gg = acc[mi][2][r] + gep[1024 + j];
            float go = acc[mi][3][r] + gep[1536 + j];
            float si = 1.f / (1.f + expf(-gi));
            float sf = 1.f / (1.f + expf(-gf));
            float so = 1.f / (1.f + expf(-go));
            float cold = hc[b * 1024 + 512 + j];
            float cn = sf * cold + si * tanhf(gg);
            float hn = so * tanhf(cn);
            bool msk = s < sm.p4.dl[b];
            float hold = hc[b * 1024 + j];
            float hnew = msk ? hn : hold;
            float cnew = msk ? cn : cold;
            hc[b * 1024 + j] = hnew;
            hc[b * 1024 + 512 + j] = cnew;
            hb[b * 512 + j] = f2bf(hnew);
            hall[((size_t)s * 64 + b) * 512 + j] = f2bf(hn);
          }
        }
      }
    }
    gbar(bar, gcount); ++gcount;
  }
}

extern "C" void kernel_launch(void* const* d_in, const int* in_sizes, int n_in,
                              void* d_out, int out_size, void* d_ws, size_t ws_size,
                              hipStream_t stream) {
  (void)in_sizes; (void)n_in; (void)out_size; (void)ws_size;
  const float* enc = (const float*)d_in[0];
  const int* captions = (const int*)d_in[1];
  const int* cap_len = (const int*)d_in[2];
  const float* emb = (const float*)d_in[3];
  const float* We_att = (const float*)d_in[4];
  const float* be_att = (const float*)d_in[5];
  const float* Wd_att = (const float*)d_in[6];
  const float* bd_att = (const float*)d_in[7];
  const float* v_att = (const float*)d_in[8];
  const float* W_beta = (const float*)d_in[10];
  const float* b_beta = (const float*)d_in[11];
  const float* W_ih = (const float*)d_in[12];
  const float* b_ih = (const float*)d_in[13];
  const float* W_hh = (const float*)d_in[14];
  const float* b_hh = (const float*)d_in[15];
  const float* W_init_h = (const float*)d_in[16];
  const float* b_init_h = (const float*)d_in[17];
  const float* W_init_c = (const float*)d_in[18];
  const float* b_init_c = (const float*)d_in[19];
  const float* W_fc = (const float*)d_in[20];
  const float* b_fc = (const float*)d_in[21];

  float* out = (float*)d_out;
  float* out_pred = out;             // 64*21*32000
  float* out_caps = out + 43008000;  // 1408
  float* out_dlen = out + 43009408;  // 64
  float* out_alph = out + 43009472;  // 263424
  float* out_sind = out + 43272896;  // 64

  char* ws = (char*)d_ws;
  size_t off = 0;
  auto alloc = [&](size_t bytes) -> void* {
    off = (off + 255) & ~(size_t)255;
    void* p = ws + off;
    off += bytes;
    return p;
  };
  int* sind = (int*)alloc(64 * 4);
  int* dlen = (int*)alloc(64 * 4);
  int* emb_rows = (int*)alloc(1344 * 4);
  GBar* bar = (GBar*)alloc(256);
  unsigned short* enc_b = (unsigned short*)alloc((size_t)25690112 * 2);
  unsigned short* preatt_b = (unsigned short*)alloc((size_t)6422528 * 2);
  unsigned short* WeattT = (unsigned short*)alloc((size_t)512 * 2048 * 2);
  unsigned short* WihemT = (unsigned short*)alloc((size_t)2048 * 512 * 2);
  unsigned short* Wih2T = (unsigned short*)alloc((size_t)2048 * 2048 * 2);
  unsigned short* WhhT = (unsigned short*)alloc((size_t)2048 * 512 * 2);
  unsigned short* WfcT = (unsigned short*)alloc((size_t)32000 * 512 * 2);
  unsigned short* WinitT = (unsigned short*)alloc((size_t)1024 * 2048 * 2);
  unsigned short* WdB = (unsigned short*)alloc((size_t)512 * 512 * 2);
  unsigned short* meanb = (unsigned short*)alloc((size_t)128 * 2048 * 2);
  float* binit = (float*)alloc(1024 * 4);
  unsigned short* Aemb_b = (unsigned short*)alloc((size_t)1408 * 512 * 2);
  unsigned short* hall_b = (unsigned short*)alloc((size_t)1408 * 512 * 2);
  float* ge = (float*)alloc((size_t)1408 * 2048 * 4);
  float* hc = (float*)alloc((size_t)64 * 1024 * 4);
  unsigned short* hb = (unsigned short*)alloc((size_t)64 * 512 * 2);
  unsigned short* zb = (unsigned short*)alloc((size_t)64 * 2048 * 2);
  float* alphag = (float*)alloc((size_t)64 * 196 * 4);

  k_prep<<<1, 64, 0, stream>>>(cap_len, captions, sind, dlen, emb_rows, out_caps, out_dlen, out_sind);
  hipMemsetAsync(out_alph, 0, (size_t)263424 * 4, stream);
  hipMemsetAsync(bar, 0, 256, stream);
  hipMemsetAsync(meanb + (size_t)64 * 2048, 0, (size_t)64 * 2048 * 2, stream);

  k_gather_enc<<<12544, 256, 0, stream>>>(enc, sind, enc_b);
  k_convert<<<128, 256, 0, stream>>>(Wd_att, WdB, 32768);
  k_tc<<<dim3(8, 32), 256, 0, stream>>>(We_att, WeattT, 2048, 512);
  k_tc<<<dim3(32, 8), 256, 0, stream>>>(W_ih, WihemT, 512, 2048);
  k_tc<<<dim3(32, 32), 256, 0, stream>>>(W_ih + (size_t)512 * 2048, Wih2T, 2048, 2048);
  k_tc<<<dim3(32, 8), 256, 0, stream>>>(W_hh, WhhT, 512, 2048);
  k_tc<<<dim3(500, 8), 256, 0, stream>>>(W_fc, WfcT, 512, 32000);
  k_tc<<<dim3(8, 32), 256, 0, stream>>>(W_init_h, WinitT, 2048, 512);
  k_tc<<<dim3(8, 32), 256, 0, stream>>>(W_init_c, WinitT + (size_t)512 * 2048, 2048, 512);
  k_biascat<<<4, 256, 0, stream>>>(b_init_h, b_init_c, binit);
  k_gather_emb<<<1408, 256, 0, stream>>>(emb, emb_rows, Aemb_b);
  k_meanb<<<dim3(64, 8), 256, 0, stream>>>(enc_b, meanb);

  // h0/c0: [mean] @ [WinitT]^T -> hc  (M=128 pad, N=1024, K=2048)
  k_gemm<<<dim3(1, 8), 256, 0, stream>>>(meanb, WinitT, binit, nullptr, hc, nullptr, nullptr,
                                         128, 1024, 2048, 0, 64);
  k_h0b<<<128, 256, 0, stream>>>(hc, hb);
  // pre_att = enc_s @ We_att + be_att -> bf16
  k_gemm<<<dim3(98, 4), 256, 0, stream>>>(enc_b, WeattT, be_att, nullptr, nullptr, preatt_b,
                                          nullptr, 12544, 512, 2048, 1, 12544);
  // ge = emb_seq @ W_ih[0:512] + b_ih + b_hh -> f32
  k_gemm<<<dim3(11, 16), 256, 0, stream>>>(Aemb_b, WihemT, b_ih, b_hh, ge, nullptr, nullptr,
                                           1408, 2048, 512, 0, 1344);
  // the 21-step recurrence, one persistent kernel
  k_loop<<<256, 256, 0, stream>>>(preatt_b, enc_b, WdB, bd_att, v_att, W_beta, b_beta, Wih2T,
                                  WhhT, ge, dlen, hc, hb, zb, alphag, hall_b, bar);
  // predictions = mask(h_all @ W_fc + b_fc) permuted to [b][t][v]
  k_gemm<<<dim3(11, 250), 256, 0, stream>>>(hall_b, WfcT, b_fc, nullptr, out_pred, nullptr,
                                            dlen, 1408, 32000, 512, 2, 1344);
}

// Round 3
// 3563.703 us; speedup vs baseline: 1.3312x; 1.3312x over previous
//
#include <hip/hip_runtime.h>

typedef __attribute__((ext_vector_type(8))) short short8;
typedef __attribute__((ext_vector_type(4))) float f32x4;

#define DEV static __device__ __forceinline__

DEV unsigned short f2bf(float x) {
  unsigned u = __float_as_uint(x);
  return (unsigned short)((u + 0x7fffu + ((u >> 16) & 1u)) >> 16);
}
DEV float bf2f(unsigned short h) { return __uint_as_float(((unsigned)h) << 16); }

// ---------------- prep: stable descending argsort + int outputs ----------------
__global__ void k_prep(const int* __restrict__ cap_len, const int* __restrict__ captions,
                       int* __restrict__ sind, int* __restrict__ dlen, int* __restrict__ emb_rows,
                       float* __restrict__ out_caps, float* __restrict__ out_dlen,
                       float* __restrict__ out_sind) {
  __shared__ int lens[64];
  __shared__ int ssind[64];
  int i = threadIdx.x;
  lens[i] = cap_len[i];
  __syncthreads();
  int li = lens[i];
  int rank = 0;
  for (int j = 0; j < 64; ++j) {
    int lj = lens[j];
    rank += (lj > li || (lj == li && j < i)) ? 1 : 0;
  }
  ssind[rank] = i;
  __syncthreads();
  int b = i;
  int s = ssind[b];
  sind[b] = s;
  int dl = lens[s] - 1;
  dlen[b] = dl;
  out_dlen[b] = (float)dl;
  out_sind[b] = (float)s;
  for (int l = 0; l < 22; ++l) {
    int cv = captions[s * 22 + l];
    out_caps[b * 22 + l] = (float)cv;
    if (l < 21) emb_rows[l * 64 + b] = cv;
  }
}

// ---------------- gather sorted encoder rows -> bf16 ----------------
__global__ __launch_bounds__(256) void k_gather_enc(const float* __restrict__ enc,
                                                    const int* __restrict__ sind,
                                                    unsigned short* __restrict__ dst) {
  int bp = blockIdx.x;  // 0..12543
  int b = bp / 196, p = bp % 196;
  const float* src = enc + ((size_t)sind[b] * 196 + p) * 2048 + threadIdx.x * 8;
  float4 v0 = *(const float4*)src;
  float4 v1 = *(const float4*)(src + 4);
  uint4 o;
  o.x = f2bf(v0.x) | ((unsigned)f2bf(v0.y) << 16);
  o.y = f2bf(v0.z) | ((unsigned)f2bf(v0.w) << 16);
  o.z = f2bf(v1.x) | ((unsigned)f2bf(v1.y) << 16);
  o.w = f2bf(v1.z) | ((unsigned)f2bf(v1.w) << 16);
  *(uint4*)(dst + (size_t)bp * 2048 + threadIdx.x * 8) = o;
}

// ---------------- flat f32 -> bf16 ----------------
__global__ __launch_bounds__(256) void k_convert(const float* __restrict__ src,
                                                 unsigned short* __restrict__ dst, int n8) {
  int i = blockIdx.x * 256 + threadIdx.x;
  if (i >= n8) return;
  float4 v0 = *(const float4*)(src + (size_t)i * 8);
  float4 v1 = *(const float4*)(src + (size_t)i * 8 + 4);
  uint4 o;
  o.x = f2bf(v0.x) | ((unsigned)f2bf(v0.y) << 16);
  o.y = f2bf(v0.z) | ((unsigned)f2bf(v0.w) << 16);
  o.z = f2bf(v1.x) | ((unsigned)f2bf(v1.y) << 16);
  o.w = f2bf(v1.z) | ((unsigned)f2bf(v1.w) << 16);
  *(uint4*)(dst + (size_t)i * 8) = o;
}

// ---- transpose-convert: src f32 [Ks][N] -> dst bf16 rows perm(n), stride/off; ----
// perm=1: gate-interleave permutation for N==2048 (i/f/g/o strips of 8)
__global__ __launch_bounds__(256) void k_tc(const float* __restrict__ src,
                                            unsigned short* __restrict__ dst, int Ks, int N,
                                            int dstStride, int dstOff, int perm) {
  __shared__ float tile[64][65];
  int n0 = blockIdx.x * 64, k0 = blockIdx.y * 64;
  int tx = threadIdx.x & 63, ty = threadIdx.x >> 6;
#pragma unroll
  for (int r = 0; r < 16; ++r) {
    int kr = r * 4 + ty;
    tile[kr][tx] = src[(size_t)(k0 + kr) * N + n0 + tx];
  }
  __syncthreads();
#pragma unroll
  for (int r = 0; r < 16; ++r) {
    int nr = r * 4 + ty;
    int n = n0 + nr;
    int prow = perm ? (((n >> 3) & 63) * 32 + (n >> 9) * 8 + (n & 7)) : n;
    dst[(size_t)prow * dstStride + dstOff + k0 + tx] = f2bf(tile[tx][nr]);
  }
}

// ---------------- gather embedding rows -> bf16 A [1408][512] (zero pad) ----------------
__global__ __launch_bounds__(256) void k_gather_emb(const float* __restrict__ emb,
                                                    const int* __restrict__ rows,
                                                    unsigned short* __restrict__ dst) {
  int r = blockIdx.x;
  unsigned short* d = dst + (size_t)r * 512;
  int t = threadIdx.x;
  if (r >= 1344) { d[t] = 0; d[t + 256] = 0; return; }
  const float* s = emb + (size_t)rows[r] * 512;
  d[t] = f2bf(s[t]);
  d[t + 256] = f2bf(s[t + 256]);
}

// ---------------- mean over 196 pixels (from sorted bf16 enc) -> bf16 ----------------
__global__ __launch_bounds__(256) void k_meanb(const unsigned short* __restrict__ encb,
                                               unsigned short* __restrict__ meanb) {
  int b = blockIdx.x, e = blockIdx.y * 256 + threadIdx.x;
  const unsigned short* base = encb + (size_t)b * 196 * 2048 + e;
  float s = 0.f;
  for (int p = 0; p < 196; ++p) s += bf2f(base[(size_t)p * 2048]);
  meanb[(size_t)b * 2048 + e] = f2bf(s * (1.0f / 196.0f));
}

__global__ void k_biascat(const float* __restrict__ bh, const float* __restrict__ bc,
                          float* __restrict__ dst) {
  int i = blockIdx.x * 256 + threadIdx.x;  // grid 4
  dst[i] = (i < 512) ? bh[i] : bc[i - 512];
}

// h0 f32 -> xcat h-section 0 (bf16)
__global__ void k_h0b(const float* __restrict__ hc, unsigned short* __restrict__ xcat) {
  int i = blockIdx.x * 256 + threadIdx.x;  // 32768
  int b = i >> 9, j = i & 511;
  xcat[(size_t)b * 3072 + 2048 + j] = f2bf(hc[b * 1024 + j]);
}

// ---------------- MFMA GEMM: C[M][N] = A[M][K] @ Bt[N][K]^T (+bias) ----------------
__global__ __launch_bounds__(256) void k_gemm(const unsigned short* __restrict__ A,
                                              const unsigned short* __restrict__ Bt,
                                              const float* __restrict__ bias1,
                                              const float* __restrict__ bias2,
                                              float* __restrict__ Cf,
                                              unsigned short* __restrict__ Cb,
                                              const int* __restrict__ dlen,
                                              int M, int N, int K, int mode, int Mreal) {
  __shared__ unsigned short As[128 * 64];
  __shared__ unsigned short Bs[128 * 64];
  int t = threadIdx.x;
  int lane = t & 63, w = t >> 6;
  int wm = w >> 1, wn = w & 1;
  int m0 = blockIdx.x * 128, n0 = blockIdx.y * 128;
  f32x4 acc[4][4] = {};
  uint4 ra[4], rb[4];

#define LOADREGS(kc)                                                             \
  {                                                                              \
    _Pragma("unroll") for (int r = 0; r < 4; ++r) {                              \
      int idx = r * 256 + t;                                                     \
      int row = idx >> 3, ke = (idx & 7) * 8;                                    \
      ra[r] = *(const uint4*)(A + (size_t)(m0 + row) * K + (kc) + ke);           \
      rb[r] = *(const uint4*)(Bt + (size_t)(n0 + row) * K + (kc) + ke);          \
    }                                                                            \
  }

  LOADREGS(0);
  for (int kc = 0; kc < K; kc += 64) {
    __syncthreads();
#pragma unroll
    for (int r = 0; r < 4; ++r) {
      int idx = r * 256 + t;
      int row = idx >> 3, cb = (idx & 7) * 16;
      int sw = cb ^ ((row & 7) << 4);
      *(uint4*)((char*)As + row * 128 + sw) = ra[r];
      *(uint4*)((char*)Bs + row * 128 + sw) = rb[r];
    }
    __syncthreads();
    if (kc + 64 < K) LOADREGS(kc + 64);
#pragma unroll
    for (int ks = 0; ks < 2; ++ks) {
      short8 af[4], bf[4];
#pragma unroll
      for (int mi = 0; mi < 4; ++mi) {
        int row = wm * 64 + mi * 16 + (lane & 15);
        int kb = (ks * 64 + (lane >> 4) * 16) ^ ((row & 7) << 4);
        af[mi] = *(const short8*)((const char*)As + row * 128 + kb);
      }
#pragma unroll
      for (int ni = 0; ni < 4; ++ni) {
        int row = wn * 64 + ni * 16 + (lane & 15);
        int kb = (ks * 64 + (lane >> 4) * 16) ^ ((row & 7) << 4);
        bf[ni] = *(const short8*)((const char*)Bs + row * 128 + kb);
      }
#pragma unroll
      for (int mi = 0; mi < 4; ++mi)
#pragma unroll
        for (int ni = 0; ni < 4; ++ni)
          acc[mi][ni] = __builtin_amdgcn_mfma_f32_16x16x32_bf16(af[mi], bf[ni], acc[mi][ni], 0, 0, 0);
    }
  }
  int rbase = (lane >> 4) * 4;
#pragma unroll
  for (int mi = 0; mi < 4; ++mi) {
#pragma unroll
    for (int ni = 0; ni < 4; ++ni) {
      int n = n0 + wn * 64 + ni * 16 + (lane & 15);
      float badd = (bias1 ? bias1[n] : 0.f) + (bias2 ? bias2[n] : 0.f);
#pragma unroll
      for (int r = 0; r < 4; ++r) {
        int m = m0 + wm * 64 + mi * 16 + rbase + r;
        if (m >= Mreal) continue;
        float v = acc[mi][ni][r] + badd;
        if (mode == 0) {
          Cf[(size_t)m * N + n] = v;
        } else if (mode == 1) {
          Cb[(size_t)m * N + n] = f2bf(v);
        } else {
          int tt = m >> 6, bb = m & 63;
          Cf[(size_t)bb * 672000 + (size_t)tt * 32000 + n] = (tt < dlen[bb]) ? v : 0.f;
        }
      }
    }
  }
#undef LOADREGS
}

// ---------------- distributed-flag grid barrier ----------------
DEV void gbar(unsigned* flags, unsigned target) {
  __syncthreads();
  if (threadIdx.x == 0) {
    __threadfence();
    __hip_atomic_store(&flags[blockIdx.x * 64], target, __ATOMIC_RELEASE,
                       __HIP_MEMORY_SCOPE_AGENT);
  }
  unsigned idx = (unsigned)threadIdx.x * 64;
  while (__hip_atomic_load(&flags[idx], __ATOMIC_RELAXED, __HIP_MEMORY_SCOPE_AGENT) < target)
    __builtin_amdgcn_s_sleep(1);
  __threadfence();
  __syncthreads();
}

// ---------------- persistent 21-step decoder loop ----------------
__global__ __launch_bounds__(256, 1) void k_loop(
    const unsigned short* __restrict__ preatt, const unsigned short* __restrict__ encb,
    const unsigned short* __restrict__ WdB, const float* __restrict__ bd,
    const float* __restrict__ v_att, const float* __restrict__ Wbeta,
    const float* __restrict__ bbeta, const unsigned short* __restrict__ Wcat,
    const float* __restrict__ ge, const int* __restrict__ dlen, float* __restrict__ hc,
    unsigned short* __restrict__ xcat, float* __restrict__ alphag,
    unsigned short* __restrict__ hall, unsigned* flags) {
  __shared__ union {
    struct { float hld[512], rv[512], rd[512], pdat[4][512], eld[200], red[256]; } p1;
    struct { float al[200], lred[4][512]; } p2;
    struct { float pd[4][64][33]; int dl[64]; } p3;
  } sm;
  int blk = blockIdx.x;
  int t = threadIdx.x;
  int lane = t & 63, w = t >> 6;
  unsigned target = 0;

  for (int s = 0; s < 21; ++s) {
    // ======== P1: attention (blocks 0..63, block = batch b) ========
    if (blk < 64) {
      int b = blk;
      sm.p1.hld[t] = hc[b * 1024 + t];
      sm.p1.hld[t + 256] = hc[b * 1024 + 256 + t];
      sm.p1.rv[t] = v_att[t];
      sm.p1.rv[t + 256] = v_att[t + 256];
      __syncthreads();
      // datt partials: wave w covers k in [w*128, w*128+128); lane cols lane*8..+7
      {
        float a[8] = {0, 0, 0, 0, 0, 0, 0, 0};
        int j0 = lane * 8;
        const unsigned short* wp = WdB + (size_t)(w * 128) * 512 + j0;
#pragma unroll 8
        for (int k = 0; k < 128; ++k) {
          float hv = sm.p1.hld[w * 128 + k];
          short8 wv = *(const short8*)(wp + (size_t)k * 512);
#pragma unroll
          for (int i = 0; i < 8; ++i) a[i] += hv * bf2f((unsigned short)wv[i]);
        }
#pragma unroll
        for (int i = 0; i < 8; ++i) sm.p1.pdat[w][j0 + i] = a[i];
      }
      sm.p1.red[t] = sm.p1.hld[t] * Wbeta[t] + sm.p1.hld[t + 256] * Wbeta[t + 256];
      __syncthreads();
      // datt reduce: thread t -> cols t*2, t*2+1
      {
        int j = t * 2;
        float d0 = bd[j] + sm.p1.pdat[0][j] + sm.p1.pdat[1][j] + sm.p1.pdat[2][j] + sm.p1.pdat[3][j];
        float d1 = bd[j + 1] + sm.p1.pdat[0][j + 1] + sm.p1.pdat[1][j + 1] + sm.p1.pdat[2][j + 1] +
                   sm.p1.pdat[3][j + 1];
        sm.p1.rd[j] = d0;
        sm.p1.rd[j + 1] = d1;
      }
      for (int st = 128; st > 0; st >>= 1) {
        if (t < st) sm.p1.red[t] += sm.p1.red[t + st];
        __syncthreads();
      }
      float gate = sm.p1.red[0] + bbeta[0];
      __syncthreads();
      // e: 8 pixels per wave per round; lane group g=lane&7 covers interleaved col chunks
      int g = lane & 7;
      for (int rnd = 0; rnd < 7; ++rnd) {
        int p = rnd * 32 + w * 8 + (lane >> 3);
        float acc = 0.f;
        if (p < 196) {
          const unsigned short* pp = preatt + ((size_t)b * 196 + p) * 512;
#pragma unroll
          for (int i = 0; i < 8; ++i) {
            int c0 = i * 64 + g * 8;
            short8 pv = *(const short8*)(pp + c0);
#pragma unroll
            for (int j = 0; j < 8; ++j)
              acc += fmaxf(bf2f((unsigned short)pv[j]) + sm.p1.rd[c0 + j], 0.f) * sm.p1.rv[c0 + j];
          }
        }
        acc += __shfl_xor(acc, 1, 64);
        acc += __shfl_xor(acc, 2, 64);
        acc += __shfl_xor(acc, 4, 64);
        if (g == 0 && p < 196) sm.p1.eld[p] = acc;
      }
      __syncthreads();
      sm.p1.red[t] = (t < 196) ? sm.p1.eld[t] : -3.4e38f;
      __syncthreads();
      for (int st = 128; st > 0; st >>= 1) {
        if (t < st) sm.p1.red[t] = fmaxf(sm.p1.red[t], sm.p1.red[t + st]);
        __syncthreads();
      }
      float mx = sm.p1.red[0];
      __syncthreads();
      float ex = (t < 196) ? expf(sm.p1.eld[t] - mx) : 0.f;
      sm.p1.red[t] = ex;
      __syncthreads();
      for (int st = 128; st > 0; st >>= 1) {
        if (t < st) sm.p1.red[t] += sm.p1.red[t + st];
        __syncthreads();
      }
      float inv = gate / sm.p1.red[0];
      if (t < 196) alphag[b * 196 + t] = ex * inv;
    }
    gbar(flags, ++target);

    // ======== P2: z = alphag @ enc (all 256 blocks; b=blk>>2, 512-col chunk) ========
    {
      int b = blk >> 2, ch = blk & 3;
      if (t < 196) sm.p2.al[t] = alphag[b * 196 + t];
      __syncthreads();
      float a[8] = {0, 0, 0, 0, 0, 0, 0, 0};
      const unsigned short* base = encb + (size_t)b * 196 * 2048 + ch * 512 + lane * 8;
#pragma unroll 7
      for (int it = 0; it < 49; ++it) {
        int p = it * 4 + w;
        short8 v = *(const short8*)(base + (size_t)p * 2048);
        float al = sm.p2.al[p];
#pragma unroll
        for (int i = 0; i < 8; ++i) a[i] += al * bf2f((unsigned short)v[i]);
      }
#pragma unroll
      for (int i = 0; i < 8; ++i) sm.p2.lred[w][lane * 8 + i] = a[i];
      __syncthreads();
      {
        int j = t * 2;
        float z0 = sm.p2.lred[0][j] + sm.p2.lred[1][j] + sm.p2.lred[2][j] + sm.p2.lred[3][j];
        float z1 = sm.p2.lred[0][j + 1] + sm.p2.lred[1][j + 1] + sm.p2.lred[2][j + 1] +
                   sm.p2.lred[3][j + 1];
        *(unsigned*)(xcat + (size_t)b * 3072 + ch * 512 + j) =
            (unsigned)f2bf(z0) | ((unsigned)f2bf(z1) << 16);
      }
    }
    gbar(flags, ++target);

    // ======== P3: gates MFMA + LSTM cell (blocks 0..63, 32 gate-interleaved cols) ========
    if (blk < 64) {
      int c = blk;
      if (t < 64) sm.p3.dl[t] = dlen[t];
      int par = s & 1;
      f32x4 acc[4][2] = {};
      int mrow = lane & 15;
      int krow = (lane >> 4) * 8;
      const unsigned short* wrow0 = Wcat + (size_t)(c * 32 + (lane & 15)) * 2560;
#pragma unroll 4
      for (int kk = 0; kk < 20; ++kk) {
        int k = w * 640 + kk * 32 + krow;
        size_t koff = (size_t)(k < 2048 ? k : (par ? k + 512 : k));
        short8 a[4], b0, b1;
#pragma unroll
        for (int mi = 0; mi < 4; ++mi)
          a[mi] = *(const short8*)(xcat + (size_t)(mi * 16 + mrow) * 3072 + koff);
        b0 = *(const short8*)(wrow0 + k);
        b1 = *(const short8*)(wrow0 + 16 * 2560 + k);
#pragma unroll
        for (int mi = 0; mi < 4; ++mi) {
          acc[mi][0] = __builtin_amdgcn_mfma_f32_16x16x32_bf16(a[mi], b0, acc[mi][0], 0, 0, 0);
          acc[mi][1] = __builtin_amdgcn_mfma_f32_16x16x32_bf16(a[mi], b1, acc[mi][1], 0, 0, 0);
        }
      }
#pragma unroll
      for (int mi = 0; mi < 4; ++mi)
#pragma unroll
        for (int ni = 0; ni < 2; ++ni)
#pragma unroll
          for (int r = 0; r < 4; ++r)
            sm.p3.pd[w][mi * 16 + (lane >> 4) * 4 + r][ni * 16 + (lane & 15)] = acc[mi][ni][r];
      __syncthreads();
#pragma unroll
      for (int u = 0; u < 2; ++u) {
        int b = t & 63;
        int jl = (t >> 6) * 2 + u;
        float sg[4];
#pragma unroll
        for (int q = 0; q < 4; ++q)
          sg[q] = sm.p3.pd[0][b][q * 8 + jl] + sm.p3.pd[1][b][q * 8 + jl] +
                  sm.p3.pd[2][b][q * 8 + jl] + sm.p3.pd[3][b][q * 8 + jl];
        int jg = c * 8 + jl;
        const float* gep = ge + ((size_t)(s * 64 + b)) * 2048;
        float gi = sg[0] + gep[jg];
        float gf = sg[1] + gep[512 + jg];
        float gg = sg[2] + gep[1024 + jg];
        float go = sg[3] + gep[1536 + jg];
        float si = 1.f / (1.f + expf(-gi));
        float sf = 1.f / (1.f + expf(-gf));
        float so = 1.f / (1.f + expf(-go));
        float cold = hc[b * 1024 + 512 + jg];
        float cn = sf * cold + si * tanhf(gg);
        float hn = so * tanhf(cn);
        bool msk = s < sm.p3.dl[b];
        float hold = hc[b * 1024 + jg];
        float hnew = msk ? hn : hold;
        float cnew = msk ? cn : cold;
        hc[b * 1024 + jg] = hnew;
        hc[b * 1024 + 512 + jg] = cnew;
        xcat[(size_t)b * 3072 + 2048 + (par ^ 1) * 512 + jg] = f2bf(hnew);
        hall[((size_t)s * 64 + b) * 512 + jg] = f2bf(hn);
      }
    }
    gbar(flags, ++target);
  }
}

extern "C" void kernel_launch(void* const* d_in, const int* in_sizes, int n_in,
                              void* d_out, int out_size, void* d_ws, size_t ws_size,
                              hipStream_t stream) {
  (void)in_sizes; (void)n_in; (void)out_size; (void)ws_size;
  const float* enc = (const float*)d_in[0];
  const int* captions = (const int*)d_in[1];
  const int* cap_len = (const int*)d_in[2];
  const float* emb = (const float*)d_in[3];
  const float* We_att = (const float*)d_in[4];
  const float* be_att = (const float*)d_in[5];
  const float* Wd_att = (const float*)d_in[6];
  const float* bd_att = (const float*)d_in[7];
  const float* v_att = (const float*)d_in[8];
  const float* W_beta = (const float*)d_in[10];
  const float* b_beta = (const float*)d_in[11];
  const float* W_ih = (const float*)d_in[12];
  const float* b_ih = (const float*)d_in[13];
  const float* W_hh = (const float*)d_in[14];
  const float* b_hh = (const float*)d_in[15];
  const float* W_init_h = (const float*)d_in[16];
  const float* b_init_h = (const float*)d_in[17];
  const float* W_init_c = (const float*)d_in[18];
  const float* b_init_c = (const float*)d_in[19];
  const float* W_fc = (const float*)d_in[20];
  const float* b_fc = (const float*)d_in[21];

  float* out = (float*)d_out;
  float* out_pred = out;             // 64*21*32000
  float* out_caps = out + 43008000;  // 1408
  float* out_dlen = out + 43009408;  // 64
  float* out_alph = out + 43009472;  // 263424
  float* out_sind = out + 43272896;  // 64

  char* ws = (char*)d_ws;
  size_t off = 0;
  auto alloc = [&](size_t bytes) -> void* {
    off = (off + 255) & ~(size_t)255;
    void* p = ws + off;
    off += bytes;
    return p;
  };
  int* sind = (int*)alloc(64 * 4);
  int* dlen = (int*)alloc(64 * 4);
  int* emb_rows = (int*)alloc(1344 * 4);
  unsigned* flags = (unsigned*)alloc(256 * 64 * 4);
  unsigned short* enc_b = (unsigned short*)alloc((size_t)25690112 * 2);
  unsigned short* preatt_b = (unsigned short*)alloc((size_t)6422528 * 2);
  unsigned short* WeattT = (unsigned short*)alloc((size_t)512 * 2048 * 2);
  unsigned short* WihemT = (unsigned short*)alloc((size_t)2048 * 512 * 2);
  unsigned short* Wcat = (unsigned short*)alloc((size_t)2048 * 2560 * 2);
  unsigned short* WfcT = (unsigned short*)alloc((size_t)32000 * 512 * 2);
  unsigned short* WinitT = (unsigned short*)alloc((size_t)1024 * 2048 * 2);
  unsigned short* WdB = (unsigned short*)alloc((size_t)512 * 512 * 2);
  unsigned short* meanb = (unsigned short*)alloc((size_t)128 * 2048 * 2);
  float* binit = (float*)alloc(1024 * 4);
  unsigned short* Aemb_b = (unsigned short*)alloc((size_t)1408 * 512 * 2);
  unsigned short* hall_b = (unsigned short*)alloc((size_t)1408 * 512 * 2);
  float* ge = (float*)alloc((size_t)1408 * 2048 * 4);
  float* hc = (float*)alloc((size_t)64 * 1024 * 4);
  unsigned short* xcat = (unsigned short*)alloc((size_t)64 * 3072 * 2);
  float* alphag = (float*)alloc((size_t)64 * 196 * 4);

  k_prep<<<1, 64, 0, stream>>>(cap_len, captions, sind, dlen, emb_rows, out_caps, out_dlen, out_sind);
  hipMemsetAsync(out_alph, 0, (size_t)263424 * 4, stream);
  hipMemsetAsync(flags, 0, 256 * 64 * 4, stream);
  hipMemsetAsync(meanb + (size_t)64 * 2048, 0, (size_t)64 * 2048 * 2, stream);

  k_gather_enc<<<12544, 256, 0, stream>>>(enc, sind, enc_b);
  k_convert<<<128, 256, 0, stream>>>(Wd_att, WdB, 32768);
  k_tc<<<dim3(8, 32), 256, 0, stream>>>(We_att, WeattT, 2048, 512, 2048, 0, 0);
  k_tc<<<dim3(32, 8), 256, 0, stream>>>(W_ih, WihemT, 512, 2048, 512, 0, 0);
  k_tc<<<dim3(32, 32), 256, 0, stream>>>(W_ih + (size_t)512 * 2048, Wcat, 2048, 2048, 2560, 0, 1);
  k_tc<<<dim3(32, 8), 256, 0, stream>>>(W_hh, Wcat, 512, 2048, 2560, 2048, 1);
  k_tc<<<dim3(500, 8), 256, 0, stream>>>(W_fc, WfcT, 512, 32000, 512, 0, 0);
  k_tc<<<dim3(8, 32), 256, 0, stream>>>(W_init_h, WinitT, 2048, 512, 2048, 0, 0);
  k_tc<<<dim3(8, 32), 256, 0, stream>>>(W_init_c, WinitT + (size_t)512 * 2048, 2048, 512, 2048, 0, 0);
  k_biascat<<<4, 256, 0, stream>>>(b_init_h, b_init_c, binit);
  k_gather_emb<<<1408, 256, 0, stream>>>(emb, emb_rows, Aemb_b);
  k_meanb<<<dim3(64, 8), 256, 0, stream>>>(enc_b, meanb);

  // h0/c0: mean @ WinitT^T -> hc (M=128 pad, N=1024, K=2048)
  k_gemm<<<dim3(1, 8), 256, 0, stream>>>(meanb, WinitT, binit, nullptr, hc, nullptr, nullptr,
                                         128, 1024, 2048, 0, 64);
  k_h0b<<<128, 256, 0, stream>>>(hc, xcat);
  // pre_att = enc_s @ We_att + be_att -> bf16
  k_gemm<<<dim3(98, 4), 256, 0, stream>>>(enc_b, WeattT, be_att, nullptr, nullptr, preatt_b,
                                          nullptr, 12544, 512, 2048, 1, 12544);
  // ge = emb_seq @ W_ih[0:512] + b_ih + b_hh -> f32
  k_gemm<<<dim3(11, 16), 256, 0, stream>>>(Aemb_b, WihemT, b_ih, b_hh, ge, nullptr, nullptr,
                                           1408, 2048, 512, 0, 1344);
  // the 21-step recurrence
  k_loop<<<256, 256, 0, stream>>>(preatt_b, enc_b, WdB, bd_att, v_att, W_beta, b_beta, Wcat,
                                  ge, dlen, hc, xcat, alphag, hall_b, flags);
  // predictions = mask(h_all @ W_fc + b_fc) permuted to [b][t][v]
  k_gemm<<<dim3(11, 250), 256, 0, stream>>>(hall_b, WfcT, b_fc, nullptr, out_pred, nullptr,
                                            dlen, 1408, 32000, 512, 2, 1344);
}

// Round 4
// 3276.899 us; speedup vs baseline: 1.4478x; 1.0875x over previous
//
#include <hip/hip_runtime.h>

typedef __attribute__((ext_vector_type(8))) short short8;
typedef __attribute__((ext_vector_type(4))) float f32x4;

#define DEV static __device__ __forceinline__

DEV unsigned short f2bf(float x) {
  unsigned u = __float_as_uint(x);
  return (unsigned short)((u + 0x7fffu + ((u >> 16) & 1u)) >> 16);
}
DEV float bf2f(unsigned short h) { return __uint_as_float(((unsigned)h) << 16); }
DEV unsigned char q8(float x, float s) {
  float y = fminf(fmaxf(x * s, -127.f), 127.f);
  return (unsigned char)(((int)rintf(y)) & 0xff);
}

// ---------------- prep: stable descending argsort + int outputs ----------------
__global__ void k_prep(const int* __restrict__ cap_len, const int* __restrict__ captions,
                       int* __restrict__ sind, int* __restrict__ dlen, int* __restrict__ emb_rows,
                       float* __restrict__ out_caps, float* __restrict__ out_dlen,
                       float* __restrict__ out_sind) {
  __shared__ int lens[64];
  __shared__ int ssind[64];
  int i = threadIdx.x;
  lens[i] = cap_len[i];
  __syncthreads();
  int li = lens[i];
  int rank = 0;
  for (int j = 0; j < 64; ++j) {
    int lj = lens[j];
    rank += (lj > li || (lj == li && j < i)) ? 1 : 0;
  }
  ssind[rank] = i;
  __syncthreads();
  int b = i;
  int s = ssind[b];
  sind[b] = s;
  int dl = lens[s] - 1;
  dlen[b] = dl;
  out_dlen[b] = (float)dl;
  out_sind[b] = (float)s;
  for (int l = 0; l < 22; ++l) {
    int cv = captions[s * 22 + l];
    out_caps[b * 22 + l] = (float)cv;
    if (l < 21) emb_rows[l * 64 + b] = cv;
  }
}

// ---------------- gather sorted encoder rows -> bf16 + int8(scale 16) ----------------
__global__ __launch_bounds__(256) void k_gather_enc(const float* __restrict__ enc,
                                                    const int* __restrict__ sind,
                                                    unsigned short* __restrict__ dst,
                                                    unsigned char* __restrict__ dst8) {
  int bp = blockIdx.x;  // 0..12543
  int b = bp / 196, p = bp % 196;
  int tx = threadIdx.x;
  const float* src = enc + ((size_t)sind[b] * 196 + p) * 2048 + tx * 8;
  float4 v0 = *(const float4*)src;
  float4 v1 = *(const float4*)(src + 4);
  uint4 o;
  o.x = f2bf(v0.x) | ((unsigned)f2bf(v0.y) << 16);
  o.y = f2bf(v0.z) | ((unsigned)f2bf(v0.w) << 16);
  o.z = f2bf(v1.x) | ((unsigned)f2bf(v1.y) << 16);
  o.w = f2bf(v1.z) | ((unsigned)f2bf(v1.w) << 16);
  *(uint4*)(dst + (size_t)bp * 2048 + tx * 8) = o;
  // int8 slice layout: [(b*4+q)][196][512]
  int q = tx >> 6, lc = (tx & 63) * 8;
  unsigned lo = (unsigned)q8(v0.x, 16.f) | ((unsigned)q8(v0.y, 16.f) << 8) |
                ((unsigned)q8(v0.z, 16.f) << 16) | ((unsigned)q8(v0.w, 16.f) << 24);
  unsigned hi = (unsigned)q8(v1.x, 16.f) | ((unsigned)q8(v1.y, 16.f) << 8) |
                ((unsigned)q8(v1.z, 16.f) << 16) | ((unsigned)q8(v1.w, 16.f) << 24);
  uint2 o8 = {lo, hi};
  *(uint2*)(dst8 + ((size_t)(b * 4 + q) * 196 + p) * 512 + lc) = o8;
}

// ---------------- flat f32 -> int8 with scale ----------------
__global__ __launch_bounds__(256) void k_conv8(const float* __restrict__ src,
                                               unsigned char* __restrict__ dst, int n8,
                                               float scale) {
  int i = blockIdx.x * 256 + threadIdx.x;
  if (i >= n8) return;
  float4 v0 = *(const float4*)(src + (size_t)i * 8);
  float4 v1 = *(const float4*)(src + (size_t)i * 8 + 4);
  unsigned lo = (unsigned)q8(v0.x, scale) | ((unsigned)q8(v0.y, scale) << 8) |
                ((unsigned)q8(v0.z, scale) << 16) | ((unsigned)q8(v0.w, scale) << 24);
  unsigned hi = (unsigned)q8(v1.x, scale) | ((unsigned)q8(v1.y, scale) << 8) |
                ((unsigned)q8(v1.z, scale) << 16) | ((unsigned)q8(v1.w, scale) << 24);
  uint2 o8 = {lo, hi};
  *(uint2*)(dst + (size_t)i * 8) = o8;
}

// ---- transpose-convert: src f32 [Ks][N] -> dst bf16 rows perm(n), stride/off ----
__global__ __launch_bounds__(256) void k_tc(const float* __restrict__ src,
                                            unsigned short* __restrict__ dst, int Ks, int N,
                                            int dstStride, int dstOff, int perm) {
  __shared__ float tile[64][65];
  int n0 = blockIdx.x * 64, k0 = blockIdx.y * 64;
  int tx = threadIdx.x & 63, ty = threadIdx.x >> 6;
#pragma unroll
  for (int r = 0; r < 16; ++r) {
    int kr = r * 4 + ty;
    tile[kr][tx] = src[(size_t)(k0 + kr) * N + n0 + tx];
  }
  __syncthreads();
#pragma unroll
  for (int r = 0; r < 16; ++r) {
    int nr = r * 4 + ty;
    int n = n0 + nr;
    int prow = perm ? (((n >> 3) & 63) * 32 + (n >> 9) * 8 + (n & 7)) : n;
    dst[(size_t)prow * dstStride + dstOff + k0 + tx] = f2bf(tile[tx][nr]);
  }
}

// ---------------- gather embedding rows -> bf16 A [1408][512] (zero pad) ----------------
__global__ __launch_bounds__(256) void k_gather_emb(const float* __restrict__ emb,
                                                    const int* __restrict__ rows,
                                                    unsigned short* __restrict__ dst) {
  int r = blockIdx.x;
  unsigned short* d = dst + (size_t)r * 512;
  int t = threadIdx.x;
  if (r >= 1344) { d[t] = 0; d[t + 256] = 0; return; }
  const float* s = emb + (size_t)rows[r] * 512;
  d[t] = f2bf(s[t]);
  d[t + 256] = f2bf(s[t + 256]);
}

// ---------------- mean over 196 pixels (from sorted bf16 enc) -> bf16 ----------------
__global__ __launch_bounds__(256) void k_meanb(const unsigned short* __restrict__ encb,
                                               unsigned short* __restrict__ meanb) {
  int b = blockIdx.x, e = blockIdx.y * 256 + threadIdx.x;
  const unsigned short* base = encb + (size_t)b * 196 * 2048 + e;
  float s = 0.f;
  for (int p = 0; p < 196; ++p) s += bf2f(base[(size_t)p * 2048]);
  meanb[(size_t)b * 2048 + e] = f2bf(s * (1.0f / 196.0f));
}

__global__ void k_biascat(const float* __restrict__ bh, const float* __restrict__ bc,
                          float* __restrict__ dst) {
  int i = blockIdx.x * 256 + threadIdx.x;  // grid 4
  dst[i] = (i < 512) ? bh[i] : bc[i - 512];
}

// h0 f32 -> xcat h-section a (bf16)
__global__ void k_h0b(const float* __restrict__ hc, unsigned short* __restrict__ xcat) {
  int i = blockIdx.x * 256 + threadIdx.x;  // 32768
  int b = i >> 9, j = i & 511;
  xcat[(size_t)b * 3072 + 2048 + j] = f2bf(hc[b * 1024 + j]);
}

// ---------------- MFMA GEMM: C[M][N] = A[M][K] @ Bt[N][K]^T (+bias) ----------------
__global__ __launch_bounds__(256) void k_gemm(const unsigned short* __restrict__ A,
                                              const unsigned short* __restrict__ Bt,
                                              const float* __restrict__ bias1,
                                              const float* __restrict__ bias2,
                                              float* __restrict__ Cf,
                                              unsigned short* __restrict__ Cb,
                                              const int* __restrict__ dlen,
                                              int M, int N, int K, int mode, int Mreal) {
  __shared__ unsigned short As[128 * 64];
  __shared__ unsigned short Bs[128 * 64];
  int t = threadIdx.x;
  int lane = t & 63, w = t >> 6;
  int wm = w >> 1, wn = w & 1;
  int m0 = blockIdx.x * 128, n0 = blockIdx.y * 128;
  f32x4 acc[4][4] = {};
  uint4 ra[4], rb[4];

#define LOADREGS(kc)                                                             \
  {                                                                              \
    _Pragma("unroll") for (int r = 0; r < 4; ++r) {                              \
      int idx = r * 256 + t;                                                     \
      int row = idx >> 3, ke = (idx & 7) * 8;                                    \
      ra[r] = *(const uint4*)(A + (size_t)(m0 + row) * K + (kc) + ke);           \
      rb[r] = *(const uint4*)(Bt + (size_t)(n0 + row) * K + (kc) + ke);          \
    }                                                                            \
  }

  LOADREGS(0);
  for (int kc = 0; kc < K; kc += 64) {
    __syncthreads();
#pragma unroll
    for (int r = 0; r < 4; ++r) {
      int idx = r * 256 + t;
      int row = idx >> 3, cb = (idx & 7) * 16;
      int sw = cb ^ ((row & 7) << 4);
      *(uint4*)((char*)As + row * 128 + sw) = ra[r];
      *(uint4*)((char*)Bs + row * 128 + sw) = rb[r];
    }
    __syncthreads();
    if (kc + 64 < K) LOADREGS(kc + 64);
#pragma unroll
    for (int ks = 0; ks < 2; ++ks) {
      short8 af[4], bf[4];
#pragma unroll
      for (int mi = 0; mi < 4; ++mi) {
        int row = wm * 64 + mi * 16 + (lane & 15);
        int kb = (ks * 64 + (lane >> 4) * 16) ^ ((row & 7) << 4);
        af[mi] = *(const short8*)((const char*)As + row * 128 + kb);
      }
#pragma unroll
      for (int ni = 0; ni < 4; ++ni) {
        int row = wn * 64 + ni * 16 + (lane & 15);
        int kb = (ks * 64 + (lane >> 4) * 16) ^ ((row & 7) << 4);
        bf[ni] = *(const short8*)((const char*)Bs + row * 128 + kb);
      }
#pragma unroll
      for (int mi = 0; mi < 4; ++mi)
#pragma unroll
        for (int ni = 0; ni < 4; ++ni)
          acc[mi][ni] = __builtin_amdgcn_mfma_f32_16x16x32_bf16(af[mi], bf[ni], acc[mi][ni], 0, 0, 0);
    }
  }
  int rbase = (lane >> 4) * 4;
#pragma unroll
  for (int mi = 0; mi < 4; ++mi) {
#pragma unroll
    for (int ni = 0; ni < 4; ++ni) {
      int n = n0 + wn * 64 + ni * 16 + (lane & 15);
      float badd = (bias1 ? bias1[n] : 0.f) + (bias2 ? bias2[n] : 0.f);
#pragma unroll
      for (int r = 0; r < 4; ++r) {
        int m = m0 + wm * 64 + mi * 16 + rbase + r;
        if (m >= Mreal) continue;
        float v = acc[mi][ni][r] + badd;
        if (mode == 0) {
          Cf[(size_t)m * N + n] = v;
        } else if (mode == 1) {
          Cb[(size_t)m * N + n] = f2bf(v);
        } else {
          int tt = m >> 6, bb = m & 63;
          Cf[(size_t)bb * 672000 + (size_t)tt * 32000 + n] = (tt < dlen[bb]) ? v : 0.f;
        }
      }
    }
  }
#undef LOADREGS
}

// ---------------- distributed-flag grid barrier ----------------
DEV void gbar(unsigned* flags, unsigned target) {
  __syncthreads();
  if (threadIdx.x == 0) {
    __threadfence();
    __hip_atomic_store(&flags[blockIdx.x * 64], target, __ATOMIC_RELEASE,
                       __HIP_MEMORY_SCOPE_AGENT);
  }
  unsigned idx = (unsigned)threadIdx.x * 64;
  while (__hip_atomic_load(&flags[idx], __ATOMIC_RELAXED, __HIP_MEMORY_SCOPE_AGENT) < target)
    __builtin_amdgcn_s_sleep(1);
  __threadfence();
  __syncthreads();
}

// ---------------- persistent 21-step decoder loop ----------------
__global__ __launch_bounds__(256, 1) void k_loop(
    const unsigned short* __restrict__ preatt, const unsigned char* __restrict__ enc8,
    const unsigned char* __restrict__ Wd8, const float* __restrict__ bd,
    const float* __restrict__ v_att, const float* __restrict__ Wbeta,
    const float* __restrict__ bbeta, const unsigned short* __restrict__ Wcat,
    const float* __restrict__ ge, const int* __restrict__ dlen, float* __restrict__ hc,
    unsigned short* __restrict__ xcat, float* __restrict__ ebuf,
    unsigned short* __restrict__ hall, unsigned* flags) {
  __shared__ __align__(16) unsigned char encL[100352];  // [196][512] int8, this block's slice
  __shared__ float rvP[512];
  __shared__ int dlP[64];
  __shared__ __align__(16) union Scr {
    struct { float hld[512]; float pdat[4][512]; float rd[512]; } p1;
    struct { float al[200]; float red[256]; float lred[4][512]; } p2;
    struct { float pd[2][64][17]; } p3;
  } scr;
  int blk = blockIdx.x;
  int t = threadIdx.x;
  int lane = t & 63, w = t >> 6;
  int b = blk >> 2, q = blk & 3;
  unsigned target = 0;

  // prologue: pin this block's enc slice in LDS; load v_att + dlen
  {
    const uint4* src = (const uint4*)(enc8 + (size_t)blk * 100352);
    uint4* dl = (uint4*)encL;
    for (int i = t; i < 6272; i += 256) dl[i] = src[i];
    rvP[t] = v_att[t];
    rvP[t + 256] = v_att[t + 256];
    if (t < 64) dlP[t] = dlen[t];
    __syncthreads();
  }

  for (int s = 0; s < 21; ++s) {
    // ======== P1: datt (redundant, full) + e for own 49 pixels ========
    {
      scr.p1.hld[t] = hc[b * 1024 + t];
      scr.p1.hld[t + 256] = hc[b * 1024 + 256 + t];
      __syncthreads();
      {
        float a[8] = {0, 0, 0, 0, 0, 0, 0, 0};
        const unsigned char* wp = Wd8 + (size_t)(w * 128) * 512 + (size_t)lane * 8;
#pragma unroll 8
        for (int k = 0; k < 128; ++k) {
          uint2 v = *(const uint2*)(wp + (size_t)k * 512);
          float hv = scr.p1.hld[w * 128 + k];
          int d0 = (int)v.x, d1 = (int)v.y;
          a[0] += hv * (float)((d0 << 24) >> 24);
          a[1] += hv * (float)((d0 << 16) >> 24);
          a[2] += hv * (float)((d0 << 8) >> 24);
          a[3] += hv * (float)(d0 >> 24);
          a[4] += hv * (float)((d1 << 24) >> 24);
          a[5] += hv * (float)((d1 << 16) >> 24);
          a[6] += hv * (float)((d1 << 8) >> 24);
          a[7] += hv * (float)(d1 >> 24);
        }
#pragma unroll
        for (int i = 0; i < 8; ++i) scr.p1.pdat[w][lane * 8 + i] = a[i];
      }
      __syncthreads();
      {
        int j = t * 2;
        scr.p1.rd[j] = bd[j] + (scr.p1.pdat[0][j] + scr.p1.pdat[1][j] + scr.p1.pdat[2][j] +
                                scr.p1.pdat[3][j]) * (1.f / 1024.f);
        scr.p1.rd[j + 1] = bd[j + 1] + (scr.p1.pdat[0][j + 1] + scr.p1.pdat[1][j + 1] +
                                        scr.p1.pdat[2][j + 1] + scr.p1.pdat[3][j + 1]) * (1.f / 1024.f);
      }
      __syncthreads();
      int g = t & 7, slot = t >> 3;
#pragma unroll
      for (int r = 0; r < 2; ++r) {
        int pl = r * 32 + slot;
        float acc = 0.f;
        if (pl < 49) {
          const unsigned short* pp = preatt + ((size_t)b * 196 + q * 49 + pl) * 512;
#pragma unroll
          for (int i = 0; i < 8; ++i) {
            int c0 = i * 64 + g * 8;
            short8 pv = *(const short8*)(pp + c0);
#pragma unroll
            for (int jj = 0; jj < 8; ++jj)
              acc += fmaxf(bf2f((unsigned short)pv[jj]) + scr.p1.rd[c0 + jj], 0.f) * rvP[c0 + jj];
          }
        }
        acc += __shfl_xor(acc, 1, 64);
        acc += __shfl_xor(acc, 2, 64);
        acc += __shfl_xor(acc, 4, 64);
        if (g == 0 && pl < 49) ebuf[b * 196 + q * 49 + pl] = acc;
      }
    }
    gbar(flags, ++target);

    // ======== P2: gate + softmax (local) + z from LDS enc ========
    {
      if (t < 196) scr.p2.al[t] = ebuf[b * 196 + t];
      scr.p2.red[t] = hc[b * 1024 + t] * Wbeta[t] + hc[b * 1024 + 256 + t] * Wbeta[t + 256];
      __syncthreads();
      for (int st = 128; st > 0; st >>= 1) {
        if (t < st) scr.p2.red[t] += scr.p2.red[t + st];
        __syncthreads();
      }
      float gate = scr.p2.red[0] + bbeta[0];
      __syncthreads();
      scr.p2.red[t] = (t < 196) ? scr.p2.al[t] : -3.4e38f;
      __syncthreads();
      for (int st = 128; st > 0; st >>= 1) {
        if (t < st) scr.p2.red[t] = fmaxf(scr.p2.red[t], scr.p2.red[t + st]);
        __syncthreads();
      }
      float mx = scr.p2.red[0];
      __syncthreads();
      float ex = (t < 196) ? expf(scr.p2.al[t] - mx) : 0.f;
      scr.p2.red[t] = ex;
      __syncthreads();
      for (int st = 128; st > 0; st >>= 1) {
        if (t < st) scr.p2.red[t] += scr.p2.red[t + st];
        __syncthreads();
      }
      float sc = gate / scr.p2.red[0];
      if (t < 196) scr.p2.al[t] = ex * sc;
      __syncthreads();
      // z: wave w covers pixels w*49..w*49+48 from LDS int8
      {
        float a[8] = {0, 0, 0, 0, 0, 0, 0, 0};
        const unsigned char* base = encL + (size_t)(w * 49) * 512 + lane * 8;
#pragma unroll 7
        for (int it = 0; it < 49; ++it) {
          uint2 v = *(const uint2*)(base + (size_t)it * 512);
          float al = scr.p2.al[w * 49 + it];
          int d0 = (int)v.x, d1 = (int)v.y;
          a[0] += al * (float)((d0 << 24) >> 24);
          a[1] += al * (float)((d0 << 16) >> 24);
          a[2] += al * (float)((d0 << 8) >> 24);
          a[3] += al * (float)(d0 >> 24);
          a[4] += al * (float)((d1 << 24) >> 24);
          a[5] += al * (float)((d1 << 16) >> 24);
          a[6] += al * (float)((d1 << 8) >> 24);
          a[7] += al * (float)(d1 >> 24);
        }
#pragma unroll
        for (int i = 0; i < 8; ++i) scr.p2.lred[w][lane * 8 + i] = a[i];
      }
      __syncthreads();
      {
        int j = t * 2;
        float z0 = (scr.p2.lred[0][j] + scr.p2.lred[1][j] + scr.p2.lred[2][j] +
                    scr.p2.lred[3][j]) * (1.f / 16.f);
        float z1 = (scr.p2.lred[0][j + 1] + scr.p2.lred[1][j + 1] + scr.p2.lred[2][j + 1] +
                    scr.p2.lred[3][j + 1]) * (1.f / 16.f);
        *(unsigned*)(xcat + (size_t)b * 3072 + q * 512 + j) =
            (unsigned)f2bf(z0) | ((unsigned)f2bf(z1) << 16);
      }
    }
    gbar(flags, ++target);

    // ======== P3: gates MFMA + LSTM cell (blocks 0..63) ========
    if (blk < 64) {
      int c = blk;
      int par = s & 1;
      int P = w >> 1, kh = w & 1;
      f32x4 acc[4] = {};
      int mrow = lane & 15;
      int krow = (lane >> 4) * 8;
      const unsigned short* wrow = Wcat + (size_t)(c * 32 + P * 16 + (lane & 15)) * 2560;
#pragma unroll 4
      for (int kk = 0; kk < 40; ++kk) {
        int k = kh * 1280 + kk * 32 + krow;
        size_t koff = (size_t)k + ((k >= 2048 && par) ? 512 : 0);
        short8 a[4], bfr;
#pragma unroll
        for (int mi = 0; mi < 4; ++mi)
          a[mi] = *(const short8*)(xcat + (size_t)(mi * 16 + mrow) * 3072 + koff);
        bfr = *(const short8*)(wrow + k);
#pragma unroll
        for (int mi = 0; mi < 4; ++mi)
          acc[mi] = __builtin_amdgcn_mfma_f32_16x16x32_bf16(a[mi], bfr, acc[mi], 0, 0, 0);
      }
      int mbase = (lane >> 4) * 4;
      if (kh) {
#pragma unroll
        for (int mi = 0; mi < 4; ++mi)
#pragma unroll
          for (int r = 0; r < 4; ++r)
            scr.p3.pd[P][mi * 16 + mbase + r][lane & 15] = acc[mi][r];
      }
      __syncthreads();
      if (!kh) {
#pragma unroll
        for (int mi = 0; mi < 4; ++mi)
#pragma unroll
          for (int r = 0; r < 4; ++r)
            scr.p3.pd[P][mi * 16 + mbase + r][lane & 15] += acc[mi][r];
      }
      __syncthreads();
#pragma unroll
      for (int u = 0; u < 2; ++u) {
        int b2 = t & 63;
        int jl = (t >> 6) * 2 + u;
        float sg[4];
#pragma unroll
        for (int gq = 0; gq < 4; ++gq) {
          int bc = gq * 8 + jl;
          sg[gq] = scr.p3.pd[bc >> 4][b2][bc & 15];
        }
        int jg = c * 8 + jl;
        const float* gep = ge + ((size_t)(s * 64 + b2)) * 2048;
        float gi = sg[0] + gep[jg];
        float gf = sg[1] + gep[512 + jg];
        float gg = sg[2] + gep[1024 + jg];
        float go = sg[3] + gep[1536 + jg];
        float si = 1.f / (1.f + expf(-gi));
        float sf = 1.f / (1.f + expf(-gf));
        float so = 1.f / (1.f + expf(-go));
        float cold = hc[b2 * 1024 + 512 + jg];
        float cn = sf * cold + si * tanhf(gg);
        float hn = so * tanhf(cn);
        bool msk = s < dlP[b2];
        float hold = hc[b2 * 1024 + jg];
        float hnew = msk ? hn : hold;
        float cnew = msk ? cn : cold;
        hc[b2 * 1024 + jg] = hnew;
        hc[b2 * 1024 + 512 + jg] = cnew;
        xcat[(size_t)b2 * 3072 + 2048 + (par ^ 1) * 512 + jg] = f2bf(hnew);
        hall[((size_t)s * 64 + b2) * 512 + jg] = f2bf(hn);
      }
    }
    gbar(flags, ++target);
  }
}

extern "C" void kernel_launch(void* const* d_in, const int* in_sizes, int n_in,
                              void* d_out, int out_size, void* d_ws, size_t ws_size,
                              hipStream_t stream) {
  (void)in_sizes; (void)n_in; (void)out_size; (void)ws_size;
  const float* enc = (const float*)d_in[0];
  const int* captions = (const int*)d_in[1];
  const int* cap_len = (const int*)d_in[2];
  const float* emb = (const float*)d_in[3];
  const float* We_att = (const float*)d_in[4];
  const float* be_att = (const float*)d_in[5];
  const float* Wd_att = (const float*)d_in[6];
  const float* bd_att = (const float*)d_in[7];
  const float* v_att = (const float*)d_in[8];
  const float* W_beta = (const float*)d_in[10];
  const float* b_beta = (const float*)d_in[11];
  const float* W_ih = (const float*)d_in[12];
  const float* b_ih = (const float*)d_in[13];
  const float* W_hh = (const float*)d_in[14];
  const float* b_hh = (const float*)d_in[15];
  const float* W_init_h = (const float*)d_in[16];
  const float* b_init_h = (const float*)d_in[17];
  const float* W_init_c = (const float*)d_in[18];
  const float* b_init_c = (const float*)d_in[19];
  const float* W_fc = (const float*)d_in[20];
  const float* b_fc = (const float*)d_in[21];

  float* out = (float*)d_out;
  float* out_pred = out;             // 64*21*32000
  float* out_caps = out + 43008000;  // 1408
  float* out_dlen = out + 43009408;  // 64
  float* out_alph = out + 43009472;  // 263424
  float* out_sind = out + 43272896;  // 64

  char* ws = (char*)d_ws;
  size_t off = 0;
  auto alloc = [&](size_t bytes) -> void* {
    off = (off + 255) & ~(size_t)255;
    void* p = ws + off;
    off += bytes;
    return p;
  };
  int* sind = (int*)alloc(64 * 4);
  int* dlen = (int*)alloc(64 * 4);
  int* emb_rows = (int*)alloc(1344 * 4);
  unsigned* flags = (unsigned*)alloc(256 * 64 * 4);
  unsigned short* enc_b = (unsigned short*)alloc((size_t)25690112 * 2);
  unsigned char* enc8 = (unsigned char*)alloc((size_t)25690112);
  unsigned short* preatt_b = (unsigned short*)alloc((size_t)6422528 * 2);
  unsigned short* WeattT = (unsigned short*)alloc((size_t)512 * 2048 * 2);
  unsigned short* WihemT = (unsigned short*)alloc((size_t)2048 * 512 * 2);
  unsigned short* Wcat = (unsigned short*)alloc((size_t)2048 * 2560 * 2);
  unsigned short* WfcT = (unsigned short*)alloc((size_t)32000 * 512 * 2);
  unsigned short* WinitT = (unsigned short*)alloc((size_t)1024 * 2048 * 2);
  unsigned char* Wd8 = (unsigned char*)alloc((size_t)512 * 512);
  unsigned short* meanb = (unsigned short*)alloc((size_t)128 * 2048 * 2);
  float* binit = (float*)alloc(1024 * 4);
  unsigned short* Aemb_b = (unsigned short*)alloc((size_t)1408 * 512 * 2);
  unsigned short* hall_b = (unsigned short*)alloc((size_t)1408 * 512 * 2);
  float* ge = (float*)alloc((size_t)1408 * 2048 * 4);
  float* hc = (float*)alloc((size_t)64 * 1024 * 4);
  unsigned short* xcat = (unsigned short*)alloc((size_t)64 * 3072 * 2);
  float* ebuf = (float*)alloc((size_t)64 * 196 * 4);

  k_prep<<<1, 64, 0, stream>>>(cap_len, captions, sind, dlen, emb_rows, out_caps, out_dlen, out_sind);
  hipMemsetAsync(out_alph, 0, (size_t)263424 * 4, stream);
  hipMemsetAsync(flags, 0, 256 * 64 * 4, stream);
  hipMemsetAsync(meanb + (size_t)64 * 2048, 0, (size_t)64 * 2048 * 2, stream);

  k_gather_enc<<<12544, 256, 0, stream>>>(enc, sind, enc_b, enc8);
  k_conv8<<<128, 256, 0, stream>>>(Wd_att, Wd8, 32768, 1024.f);
  k_tc<<<dim3(8, 32), 256, 0, stream>>>(We_att, WeattT, 2048, 512, 2048, 0, 0);
  k_tc<<<dim3(32, 8), 256, 0, stream>>>(W_ih, WihemT, 512, 2048, 512, 0, 0);
  k_tc<<<dim3(32, 32), 256, 0, stream>>>(W_ih + (size_t)512 * 2048, Wcat, 2048, 2048, 2560, 0, 1);
  k_tc<<<dim3(32, 8), 256, 0, stream>>>(W_hh, Wcat, 512, 2048, 2560, 2048, 1);
  k_tc<<<dim3(500, 8), 256, 0, stream>>>(W_fc, WfcT, 512, 32000, 512, 0, 0);
  k_tc<<<dim3(8, 32), 256, 0, stream>>>(W_init_h, WinitT, 2048, 512, 2048, 0, 0);
  k_tc<<<dim3(8, 32), 256, 0, stream>>>(W_init_c, WinitT + (size_t)512 * 2048, 2048, 512, 2048, 0, 0);
  k_biascat<<<4, 256, 0, stream>>>(b_init_h, b_init_c, binit);
  k_gather_emb<<<1408, 256, 0, stream>>>(emb, emb_rows, Aemb_b);
  k_meanb<<<dim3(64, 8), 256, 0, stream>>>(enc_b, meanb);

  // h0/c0: mean @ WinitT^T -> hc (M=128 pad, N=1024, K=2048)
  k_gemm<<<dim3(1, 8), 256, 0, stream>>>(meanb, WinitT, binit, nullptr, hc, nullptr, nullptr,
                                         128, 1024, 2048, 0, 64);
  k_h0b<<<128, 256, 0, stream>>>(hc, xcat);
  // pre_att = enc_s @ We_att + be_att -> bf16
  k_gemm<<<dim3(98, 4), 256, 0, stream>>>(enc_b, WeattT, be_att, nullptr, nullptr, preatt_b,
                                          nullptr, 12544, 512, 2048, 1, 12544);
  // ge = emb_seq @ W_ih[0:512] + b_ih + b_hh -> f32
  k_gemm<<<dim3(11, 16), 256, 0, stream>>>(Aemb_b, WihemT, b_ih, b_hh, ge, nullptr, nullptr,
                                           1408, 2048, 512, 0, 1344);
  // the 21-step recurrence
  k_loop<<<256, 256, 0, stream>>>(preatt_b, enc8, Wd8, bd_att, v_att, W_beta, b_beta, Wcat,
                                  ge, dlen, hc, xcat, ebuf, hall_b, flags);
  // predictions = mask(h_all @ W_fc + b_fc) permuted to [b][t][v]
  k_gemm<<<dim3(11, 250), 256, 0, stream>>>(hall_b, WfcT, b_fc, nullptr, out_pred, nullptr,
                                            dlen, 1408, 32000, 512, 2, 1344);
}

// Round 5
// 2913.515 us; speedup vs baseline: 1.6283x; 1.1247x over previous
//
#include <hip/hip_runtime.h>

typedef __attribute__((ext_vector_type(8))) short short8;
typedef __attribute__((ext_vector_type(4))) float f32x4;

#define DEV static __device__ __forceinline__

DEV unsigned short f2bf(float x) {
  unsigned u = __float_as_uint(x);
  return (unsigned short)((u + 0x7fffu + ((u >> 16) & 1u)) >> 16);
}
DEV float bf2f(unsigned short h) { return __uint_as_float(((unsigned)h) << 16); }
DEV unsigned char q8(float x, float s) {
  float y = fminf(fmaxf(x * s, -127.f), 127.f);
  return (unsigned char)(((int)rintf(y)) & 0xff);
}

// agent-scope relaxed atomics: write-through to IF$ (no dirty L2), loads bypass L2.
DEV float ald_f(const float* p) {
  return __hip_atomic_load(p, __ATOMIC_RELAXED, __HIP_MEMORY_SCOPE_AGENT);
}
DEV void ast_f(float* p, float v) {
  __hip_atomic_store(p, v, __ATOMIC_RELAXED, __HIP_MEMORY_SCOPE_AGENT);
}
DEV void ast_u(unsigned* p, unsigned v) {
  __hip_atomic_store(p, v, __ATOMIC_RELAXED, __HIP_MEMORY_SCOPE_AGENT);
}
DEV unsigned long long ald_u64(const unsigned long long* p) {
  return __hip_atomic_load(p, __ATOMIC_RELAXED, __HIP_MEMORY_SCOPE_AGENT);
}
union U16 { unsigned long long q[2]; short8 s; };

DEV void acc8(float (&a)[8], uint2 v, float m) {
  int d0 = (int)v.x, d1 = (int)v.y;
  a[0] += m * (float)((d0 << 24) >> 24);
  a[1] += m * (float)((d0 << 16) >> 24);
  a[2] += m * (float)((d0 << 8) >> 24);
  a[3] += m * (float)(d0 >> 24);
  a[4] += m * (float)((d1 << 24) >> 24);
  a[5] += m * (float)((d1 << 16) >> 24);
  a[6] += m * (float)((d1 << 8) >> 24);
  a[7] += m * (float)(d1 >> 24);
}

// ---------------- prep: stable descending argsort + int outputs ----------------
__global__ void k_prep(const int* __restrict__ cap_len, const int* __restrict__ captions,
                       int* __restrict__ sind, int* __restrict__ dlen, int* __restrict__ emb_rows,
                       float* __restrict__ out_caps, float* __restrict__ out_dlen,
                       float* __restrict__ out_sind) {
  __shared__ int lens[64];
  __shared__ int ssind[64];
  int i = threadIdx.x;
  lens[i] = cap_len[i];
  __syncthreads();
  int li = lens[i];
  int rank = 0;
  for (int j = 0; j < 64; ++j) {
    int lj = lens[j];
    rank += (lj > li || (lj == li && j < i)) ? 1 : 0;
  }
  ssind[rank] = i;
  __syncthreads();
  int b = i;
  int s = ssind[b];
  sind[b] = s;
  int dl = lens[s] - 1;
  dlen[b] = dl;
  out_dlen[b] = (float)dl;
  out_sind[b] = (float)s;
  for (int l = 0; l < 22; ++l) {
    int cv = captions[s * 22 + l];
    out_caps[b * 22 + l] = (float)cv;
    if (l < 21) emb_rows[l * 64 + b] = cv;
  }
}

// ---------------- gather sorted encoder rows -> bf16 + int8(scale 16) ----------------
__global__ __launch_bounds__(256) void k_gather_enc(const float* __restrict__ enc,
                                                    const int* __restrict__ sind,
                                                    unsigned short* __restrict__ dst,
                                                    unsigned char* __restrict__ dst8) {
  int bp = blockIdx.x;  // 0..12543
  int b = bp / 196, p = bp % 196;
  int tx = threadIdx.x;
  const float* src = enc + ((size_t)sind[b] * 196 + p) * 2048 + tx * 8;
  float4 v0 = *(const float4*)src;
  float4 v1 = *(const float4*)(src + 4);
  uint4 o;
  o.x = f2bf(v0.x) | ((unsigned)f2bf(v0.y) << 16);
  o.y = f2bf(v0.z) | ((unsigned)f2bf(v0.w) << 16);
  o.z = f2bf(v1.x) | ((unsigned)f2bf(v1.y) << 16);
  o.w = f2bf(v1.z) | ((unsigned)f2bf(v1.w) << 16);
  *(uint4*)(dst + (size_t)bp * 2048 + tx * 8) = o;
  int q = tx >> 6, lc = (tx & 63) * 8;
  unsigned lo = (unsigned)q8(v0.x, 16.f) | ((unsigned)q8(v0.y, 16.f) << 8) |
                ((unsigned)q8(v0.z, 16.f) << 16) | ((unsigned)q8(v0.w, 16.f) << 24);
  unsigned hi = (unsigned)q8(v1.x, 16.f) | ((unsigned)q8(v1.y, 16.f) << 8) |
                ((unsigned)q8(v1.z, 16.f) << 16) | ((unsigned)q8(v1.w, 16.f) << 24);
  uint2 o8 = {lo, hi};
  *(uint2*)(dst8 + ((size_t)(b * 4 + q) * 196 + p) * 512 + lc) = o8;
}

// ---------------- flat f32 -> int8 with scale ----------------
__global__ __launch_bounds__(256) void k_conv8(const float* __restrict__ src,
                                               unsigned char* __restrict__ dst, int n8,
                                               float scale) {
  int i = blockIdx.x * 256 + threadIdx.x;
  if (i >= n8) return;
  float4 v0 = *(const float4*)(src + (size_t)i * 8);
  float4 v1 = *(const float4*)(src + (size_t)i * 8 + 4);
  unsigned lo = (unsigned)q8(v0.x, scale) | ((unsigned)q8(v0.y, scale) << 8) |
                ((unsigned)q8(v0.z, scale) << 16) | ((unsigned)q8(v0.w, scale) << 24);
  unsigned hi = (unsigned)q8(v1.x, scale) | ((unsigned)q8(v1.y, scale) << 8) |
                ((unsigned)q8(v1.z, scale) << 16) | ((unsigned)q8(v1.w, scale) << 24);
  uint2 o8 = {lo, hi};
  *(uint2*)(dst + (size_t)i * 8) = o8;
}

// ---- transpose-convert: src f32 [Ks][N] -> dst bf16 rows perm(n), stride/off ----
__global__ __launch_bounds__(256) void k_tc(const float* __restrict__ src,
                                            unsigned short* __restrict__ dst, int Ks, int N,
                                            int dstStride, int dstOff, int perm) {
  __shared__ float tile[64][65];
  int n0 = blockIdx.x * 64, k0 = blockIdx.y * 64;
  int tx = threadIdx.x & 63, ty = threadIdx.x >> 6;
#pragma unroll
  for (int r = 0; r < 16; ++r) {
    int kr = r * 4 + ty;
    tile[kr][tx] = src[(size_t)(k0 + kr) * N + n0 + tx];
  }
  __syncthreads();
#pragma unroll
  for (int r = 0; r < 16; ++r) {
    int nr = r * 4 + ty;
    int n = n0 + nr;
    int prow = perm ? (((n >> 3) & 63) * 32 + (n >> 9) * 8 + (n & 7)) : n;
    dst[(size_t)prow * dstStride + dstOff + k0 + tx] = f2bf(tile[tx][nr]);
  }
}

// ---------------- gather embedding rows -> bf16 A [1408][512] (zero pad) ----------------
__global__ __launch_bounds__(256) void k_gather_emb(const float* __restrict__ emb,
                                                    const int* __restrict__ rows,
                                                    unsigned short* __restrict__ dst) {
  int r = blockIdx.x;
  unsigned short* d = dst + (size_t)r * 512;
  int t = threadIdx.x;
  if (r >= 1344) { d[t] = 0; d[t + 256] = 0; return; }
  const float* s = emb + (size_t)rows[r] * 512;
  d[t] = f2bf(s[t]);
  d[t + 256] = f2bf(s[t + 256]);
}

// ---------------- mean over 196 pixels (from sorted bf16 enc) -> bf16 ----------------
__global__ __launch_bounds__(256) void k_meanb(const unsigned short* __restrict__ encb,
                                               unsigned short* __restrict__ meanb) {
  int b = blockIdx.x, e = blockIdx.y * 256 + threadIdx.x;
  const unsigned short* base = encb + (size_t)b * 196 * 2048 + e;
  float s = 0.f;
  for (int p = 0; p < 196; ++p) s += bf2f(base[(size_t)p * 2048]);
  meanb[(size_t)b * 2048 + e] = f2bf(s * (1.0f / 196.0f));
}

__global__ void k_biascat(const float* __restrict__ bh, const float* __restrict__ bc,
                          float* __restrict__ dst) {
  int i = blockIdx.x * 256 + threadIdx.x;  // grid 4
  dst[i] = (i < 512) ? bh[i] : bc[i - 512];
}

// h0 f32 -> xcat h-section 0 (bf16)
__global__ void k_h0b(const float* __restrict__ hc, unsigned short* __restrict__ xcat) {
  int i = blockIdx.x * 256 + threadIdx.x;  // 32768
  int b = i >> 9, j = i & 511;
  xcat[(size_t)b * 3072 + 2048 + j] = f2bf(hc[b * 1024 + j]);
}

// ---------------- MFMA GEMM: C[M][N] = A[M][K] @ Bt[N][K]^T (+bias) ----------------
__global__ __launch_bounds__(256) void k_gemm(const unsigned short* __restrict__ A,
                                              const unsigned short* __restrict__ Bt,
                                              const float* __restrict__ bias1,
                                              const float* __restrict__ bias2,
                                              float* __restrict__ Cf,
                                              unsigned short* __restrict__ Cb,
                                              const int* __restrict__ dlen,
                                              int M, int N, int K, int mode, int Mreal) {
  __shared__ unsigned short As[128 * 64];
  __shared__ unsigned short Bs[128 * 64];
  int t = threadIdx.x;
  int lane = t & 63, w = t >> 6;
  int wm = w >> 1, wn = w & 1;
  int m0 = blockIdx.x * 128, n0 = blockIdx.y * 128;
  f32x4 acc[4][4] = {};
  uint4 ra[4], rb[4];

#define LOADREGS(kc)                                                             \
  {                                                                              \
    _Pragma("unroll") for (int r = 0; r < 4; ++r) {                              \
      int idx = r * 256 + t;                                                     \
      int row = idx >> 3, ke = (idx & 7) * 8;                                    \
      ra[r] = *(const uint4*)(A + (size_t)(m0 + row) * K + (kc) + ke);           \
      rb[r] = *(const uint4*)(Bt + (size_t)(n0 + row) * K + (kc) + ke);          \
    }                                                                            \
  }

  LOADREGS(0);
  for (int kc = 0; kc < K; kc += 64) {
    __syncthreads();
#pragma unroll
    for (int r = 0; r < 4; ++r) {
      int idx = r * 256 + t;
      int row = idx >> 3, cb = (idx & 7) * 16;
      int sw = cb ^ ((row & 7) << 4);
      *(uint4*)((char*)As + row * 128 + sw) = ra[r];
      *(uint4*)((char*)Bs + row * 128 + sw) = rb[r];
    }
    __syncthreads();
    if (kc + 64 < K) LOADREGS(kc + 64);
#pragma unroll
    for (int ks = 0; ks < 2; ++ks) {
      short8 af[4], bf[4];
#pragma unroll
      for (int mi = 0; mi < 4; ++mi) {
        int row = wm * 64 + mi * 16 + (lane & 15);
        int kb = (ks * 64 + (lane >> 4) * 16) ^ ((row & 7) << 4);
        af[mi] = *(const short8*)((const char*)As + row * 128 + kb);
      }
#pragma unroll
      for (int ni = 0; ni < 4; ++ni) {
        int row = wn * 64 + ni * 16 + (lane & 15);
        int kb = (ks * 64 + (lane >> 4) * 16) ^ ((row & 7) << 4);
        bf[ni] = *(const short8*)((const char*)Bs + row * 128 + kb);
      }
#pragma unroll
      for (int mi = 0; mi < 4; ++mi)
#pragma unroll
        for (int ni = 0; ni < 4; ++ni)
          acc[mi][ni] = __builtin_amdgcn_mfma_f32_16x16x32_bf16(af[mi], bf[ni], acc[mi][ni], 0, 0, 0);
    }
  }
  int rbase = (lane >> 4) * 4;
#pragma unroll
  for (int mi = 0; mi < 4; ++mi) {
#pragma unroll
    for (int ni = 0; ni < 4; ++ni) {
      int n = n0 + wn * 64 + ni * 16 + (lane & 15);
      float badd = (bias1 ? bias1[n] : 0.f) + (bias2 ? bias2[n] : 0.f);
#pragma unroll
      for (int r = 0; r < 4; ++r) {
        int m = m0 + wm * 64 + mi * 16 + rbase + r;
        if (m >= Mreal) continue;
        float v = acc[mi][ni][r] + badd;
        if (mode == 0) {
          Cf[(size_t)m * N + n] = v;
        } else if (mode == 1) {
          Cb[(size_t)m * N + n] = f2bf(v);
        } else {
          int tt = m >> 6, bb = m & 63;
          Cf[(size_t)bb * 672000 + (size_t)tt * 32000 + n] = (tt < dlen[bb]) ? v : 0.f;
        }
      }
    }
  }
#undef LOADREGS
}

// ------------- fence-free grid barrier: per-block flags + master broadcast -------------
DEV void gbar(unsigned* flags, unsigned* gen, unsigned target) {
  __syncthreads();  // drains vmcnt(0) for all threads (write-through stores now at IF$)
  if (threadIdx.x == 0)
    __hip_atomic_store(&flags[blockIdx.x * 32], target, __ATOMIC_RELAXED,
                       __HIP_MEMORY_SCOPE_AGENT);
  if (blockIdx.x == 0) {
    while (__hip_atomic_load(&flags[threadIdx.x * 32], __ATOMIC_RELAXED,
                             __HIP_MEMORY_SCOPE_AGENT) < target)
      __builtin_amdgcn_s_sleep(1);
    __syncthreads();
    if (threadIdx.x == 0)
      __hip_atomic_store(gen, target, __ATOMIC_RELAXED, __HIP_MEMORY_SCOPE_AGENT);
  }
  if (threadIdx.x == 0) {
    while (__hip_atomic_load(gen, __ATOMIC_RELAXED, __HIP_MEMORY_SCOPE_AGENT) < target)
      __builtin_amdgcn_s_sleep(1);
  }
  __syncthreads();
}

// ---------------- persistent 21-step decoder loop ----------------
__global__ __launch_bounds__(256, 1) void k_loop(
    const unsigned short* __restrict__ preatt, const unsigned char* __restrict__ enc8,
    const unsigned char* __restrict__ Wd8, const float* __restrict__ bd,
    const float* __restrict__ v_att, const float* __restrict__ Wbeta,
    const float* __restrict__ bbeta, const unsigned short* __restrict__ Wcat,
    const float* __restrict__ ge, const int* __restrict__ dlen, float* __restrict__ hc,
    unsigned short* __restrict__ xcat, unsigned short* __restrict__ hall,
    unsigned* flags, unsigned* gen) {
  __shared__ __align__(16) unsigned char encL[100352];  // [196][512] int8 slice
  __shared__ float rvP[512];
  __shared__ int dlP[64];
  __shared__ __align__(16) union Scr {
    struct {
      float hld[512];
      float rd[512];
      float eld[200];
      float red[256];
      float gpart[4];
      union { float pdat[4][512]; float lred[4][512]; } u;
    } a;
    struct { float pd[2][64][17]; } p3;
  } scr;
  int blk = blockIdx.x;
  int t = threadIdx.x;
  int lane = t & 63, w = t >> 6;
  int b = blk >> 2, q = blk & 3;
  unsigned target = 0;

  // prologue: pin enc slice in LDS (plain loads; enc8 flushed by prior kernel)
  {
    const uint4* src = (const uint4*)(enc8 + (size_t)blk * 100352);
    uint4* dl = (uint4*)encL;
    for (int i = t; i < 6272; i += 256) dl[i] = src[i];
    rvP[t] = v_att[t];
    rvP[t + 256] = v_att[t + 256];
    if (t < 64) dlP[t] = dlen[t];
    __syncthreads();
  }

  for (int s = 0; s < 21; ++s) {
    // ======== Phase A: datt + e(196) + softmax + gate + z-quarter ========
    {
      float h0 = ald_f(&hc[b * 1024 + t]);
      float h1 = ald_f(&hc[b * 1024 + 256 + t]);
      scr.a.hld[t] = h0;
      scr.a.hld[t + 256] = h1;
      // gate partial: wave shuffle reduce
      float gp = h0 * Wbeta[t] + h1 * Wbeta[t + 256];
#pragma unroll
      for (int off = 32; off > 0; off >>= 1) gp += __shfl_xor(gp, off, 64);
      if (lane == 0) scr.a.gpart[w] = gp;
      __syncthreads();
      // datt partials: wave w k-slice [w*128,+128), lane -> 8 cols (Wd8 L2-warm)
      {
        float a[8] = {0, 0, 0, 0, 0, 0, 0, 0};
        const unsigned char* wp = Wd8 + (size_t)(w * 128) * 512 + (size_t)lane * 8;
#pragma unroll 8
        for (int k = 0; k < 128; ++k) {
          uint2 v = *(const uint2*)(wp + (size_t)k * 512);
          acc8(a, v, scr.a.hld[w * 128 + k]);
        }
#pragma unroll
        for (int i = 0; i < 8; ++i) scr.a.u.pdat[w][lane * 8 + i] = a[i];
      }
      __syncthreads();
      {
        int j = t * 2;
        scr.a.rd[j] = bd[j] + (scr.a.u.pdat[0][j] + scr.a.u.pdat[1][j] + scr.a.u.pdat[2][j] +
                               scr.a.u.pdat[3][j]) * (1.f / 1024.f);
        scr.a.rd[j + 1] = bd[j + 1] + (scr.a.u.pdat[0][j + 1] + scr.a.u.pdat[1][j + 1] +
                                       scr.a.u.pdat[2][j + 1] + scr.a.u.pdat[3][j + 1]) *
                                          (1.f / 1024.f);
      }
      __syncthreads();
      // e for ALL 196 pixels (preatt L2-warm): 32 groups of 8 lanes
      int g = t & 7, grp = t >> 3;
#pragma unroll
      for (int r = 0; r < 7; ++r) {
        int p = r * 32 + grp;
        float acc = 0.f;
        if (p < 196) {
          const unsigned short* pp = preatt + ((size_t)b * 196 + p) * 512;
#pragma unroll
          for (int i = 0; i < 8; ++i) {
            int c0 = i * 64 + g * 8;
            short8 pv = *(const short8*)(pp + c0);
#pragma unroll
            for (int jj = 0; jj < 8; ++jj)
              acc += fmaxf(bf2f((unsigned short)pv[jj]) + scr.a.rd[c0 + jj], 0.f) * rvP[c0 + jj];
          }
        }
        acc += __shfl_xor(acc, 1, 64);
        acc += __shfl_xor(acc, 2, 64);
        acc += __shfl_xor(acc, 4, 64);
        if (g == 0 && p < 196) scr.a.eld[p] = acc;
      }
      __syncthreads();
      // softmax (block-local) + gate fold
      float gate = scr.a.gpart[0] + scr.a.gpart[1] + scr.a.gpart[2] + scr.a.gpart[3] + bbeta[0];
      scr.a.red[t] = (t < 196) ? scr.a.eld[t] : -3.4e38f;
      __syncthreads();
      for (int st = 128; st > 0; st >>= 1) {
        if (t < st) scr.a.red[t] = fmaxf(scr.a.red[t], scr.a.red[t + st]);
        __syncthreads();
      }
      float mx = scr.a.red[0];
      __syncthreads();
      float ex = (t < 196) ? expf(scr.a.eld[t] - mx) : 0.f;
      scr.a.red[t] = ex;
      __syncthreads();
      for (int st = 128; st > 0; st >>= 1) {
        if (t < st) scr.a.red[t] += scr.a.red[t + st];
        __syncthreads();
      }
      float inv = gate / scr.a.red[0];
      __syncthreads();
      if (t < 196) scr.a.eld[t] = ex * inv;  // alpha*gate
      __syncthreads();
      // z: wave w pixels [w*49,+49) from LDS int8
      {
        float a[8] = {0, 0, 0, 0, 0, 0, 0, 0};
        const unsigned char* base = encL + (size_t)(w * 49) * 512 + lane * 8;
#pragma unroll 7
        for (int it = 0; it < 49; ++it) {
          uint2 v = *(const uint2*)(base + (size_t)it * 512);
          acc8(a, v, scr.a.eld[w * 49 + it]);
        }
#pragma unroll
        for (int i = 0; i < 8; ++i) scr.a.u.lred[w][lane * 8 + i] = a[i];
      }
      __syncthreads();
      {
        int j = t * 2;
        float z0 = (scr.a.u.lred[0][j] + scr.a.u.lred[1][j] + scr.a.u.lred[2][j] +
                    scr.a.u.lred[3][j]) * (1.f / 16.f);
        float z1 = (scr.a.u.lred[0][j + 1] + scr.a.u.lred[1][j + 1] + scr.a.u.lred[2][j + 1] +
                    scr.a.u.lred[3][j + 1]) * (1.f / 16.f);
        ast_u((unsigned*)(xcat + (size_t)b * 3072 + q * 512 + j),
              (unsigned)f2bf(z0) | ((unsigned)f2bf(z1) << 16));
      }
    }
    gbar(flags, gen, ++target);

    // ======== Phase B: gates MFMA + LSTM cell (blocks 0..63) ========
    if (blk < 64) {
      int c = blk;
      int par = s & 1;
      int P = w >> 1, kh = w & 1;
      f32x4 acc[4] = {};
      int mrow = lane & 15;
      int krow = (lane >> 4) * 8;
      const unsigned short* wrow = Wcat + (size_t)(c * 32 + P * 16 + (lane & 15)) * 2560;
#pragma unroll 4
      for (int kk = 0; kk < 40; ++kk) {
        int k = kh * 1280 + kk * 32 + krow;
        size_t koff = (size_t)k + ((k >= 2048 && par) ? 512 : 0);
        short8 a[4], bfr;
#pragma unroll
        for (int mi = 0; mi < 4; ++mi) {
          const unsigned long long* xq =
              (const unsigned long long*)(xcat + (size_t)(mi * 16 + mrow) * 3072 + koff);
          U16 u;
          u.q[0] = ald_u64(xq);
          u.q[1] = ald_u64(xq + 1);
          a[mi] = u.s;
        }
        bfr = *(const short8*)(wrow + k);  // Wcat L2-warm
#pragma unroll
        for (int mi = 0; mi < 4; ++mi)
          acc[mi] = __builtin_amdgcn_mfma_f32_16x16x32_bf16(a[mi], bfr, acc[mi], 0, 0, 0);
      }
      int mbase = (lane >> 4) * 4;
      if (kh) {
#pragma unroll
        for (int mi = 0; mi < 4; ++mi)
#pragma unroll
          for (int r = 0; r < 4; ++r)
            scr.p3.pd[P][mi * 16 + mbase + r][lane & 15] = acc[mi][r];
      }
      __syncthreads();
      if (!kh) {
#pragma unroll
        for (int mi = 0; mi < 4; ++mi)
#pragma unroll
          for (int r = 0; r < 4; ++r)
            scr.p3.pd[P][mi * 16 + mbase + r][lane & 15] += acc[mi][r];
      }
      __syncthreads();
      {
        int b2 = t & 63;
        int jl0 = (t >> 6) * 2;
        unsigned hallp = 0, hxp = 0;
#pragma unroll
        for (int u = 0; u < 2; ++u) {
          int jl = jl0 + u;
          float sg[4];
#pragma unroll
          for (int gq = 0; gq < 4; ++gq) {
            int bc = gq * 8 + jl;
            sg[gq] = scr.p3.pd[bc >> 4][b2][bc & 15];
          }
          int jg = c * 8 + jl;
          const float* gep = ge + ((size_t)(s * 64 + b2)) * 2048;
          float gi = sg[0] + gep[jg];
          float gf = sg[1] + gep[512 + jg];
          float gg = sg[2] + gep[1024 + jg];
          float go = sg[3] + gep[1536 + jg];
          float si = 1.f / (1.f + expf(-gi));
          float sf = 1.f / (1.f + expf(-gf));
          float so = 1.f / (1.f + expf(-go));
          float cold = ald_f(&hc[b2 * 1024 + 512 + jg]);
          float cn = sf * cold + si * tanhf(gg);
          float hn = so * tanhf(cn);
          bool msk = s < dlP[b2];
          float hold = ald_f(&hc[b2 * 1024 + jg]);
          float hnew = msk ? hn : hold;
          float cnew = msk ? cn : cold;
          ast_f(&hc[b2 * 1024 + jg], hnew);
          ast_f(&hc[b2 * 1024 + 512 + jg], cnew);
          hallp |= ((unsigned)f2bf(hn)) << (u * 16);
          hxp |= ((unsigned)f2bf(hnew)) << (u * 16);
        }
        int jg0 = c * 8 + jl0;
        ast_u((unsigned*)(xcat + (size_t)b2 * 3072 + 2048 + (par ^ 1) * 512 + jg0), hxp);
        ast_u((unsigned*)(hall + ((size_t)s * 64 + b2) * 512 + jg0), hallp);
      }
    }
    gbar(flags, gen, ++target);
  }
}

extern "C" void kernel_launch(void* const* d_in, const int* in_sizes, int n_in,
                              void* d_out, int out_size, void* d_ws, size_t ws_size,
                              hipStream_t stream) {
  (void)in_sizes; (void)n_in; (void)out_size; (void)ws_size;
  const float* enc = (const float*)d_in[0];
  const int* captions = (const int*)d_in[1];
  const int* cap_len = (const int*)d_in[2];
  const float* emb = (const float*)d_in[3];
  const float* We_att = (const float*)d_in[4];
  const float* be_att = (const float*)d_in[5];
  const float* Wd_att = (const float*)d_in[6];
  const float* bd_att = (const float*)d_in[7];
  const float* v_att = (const float*)d_in[8];
  const float* W_beta = (const float*)d_in[10];
  const float* b_beta = (const float*)d_in[11];
  const float* W_ih = (const float*)d_in[12];
  const float* b_ih = (const float*)d_in[13];
  const float* W_hh = (const float*)d_in[14];
  const float* b_hh = (const float*)d_in[15];
  const float* W_init_h = (const float*)d_in[16];
  const float* b_init_h = (const float*)d_in[17];
  const float* W_init_c = (const float*)d_in[18];
  const float* b_init_c = (const float*)d_in[19];
  const float* W_fc = (const float*)d_in[20];
  const float* b_fc = (const float*)d_in[21];

  float* out = (float*)d_out;
  float* out_pred = out;             // 64*21*32000
  float* out_caps = out + 43008000;  // 1408
  float* out_dlen = out + 43009408;  // 64
  float* out_alph = out + 43009472;  // 263424
  float* out_sind = out + 43272896;  // 64

  char* ws = (char*)d_ws;
  size_t off = 0;
  auto alloc = [&](size_t bytes) -> void* {
    off = (off + 255) & ~(size_t)255;
    void* p = ws + off;
    off += bytes;
    return p;
  };
  int* sind = (int*)alloc(64 * 4);
  int* dlen = (int*)alloc(64 * 4);
  int* emb_rows = (int*)alloc(1344 * 4);
  unsigned* flags = (unsigned*)alloc(256 * 32 * 4);
  unsigned* gen = (unsigned*)alloc(256);
  unsigned short* enc_b = (unsigned short*)alloc((size_t)25690112 * 2);
  unsigned char* enc8 = (unsigned char*)alloc((size_t)25690112);
  unsigned short* preatt_b = (unsigned short*)alloc((size_t)6422528 * 2);
  unsigned short* WeattT = (unsigned short*)alloc((size_t)512 * 2048 * 2);
  unsigned short* WihemT = (unsigned short*)alloc((size_t)2048 * 512 * 2);
  unsigned short* Wcat = (unsigned short*)alloc((size_t)2048 * 2560 * 2);
  unsigned short* WfcT = (unsigned short*)alloc((size_t)32000 * 512 * 2);
  unsigned short* WinitT = (unsigned short*)alloc((size_t)1024 * 2048 * 2);
  unsigned char* Wd8 = (unsigned char*)alloc((size_t)512 * 512);
  unsigned short* meanb = (unsigned short*)alloc((size_t)128 * 2048 * 2);
  float* binit = (float*)alloc(1024 * 4);
  unsigned short* Aemb_b = (unsigned short*)alloc((size_t)1408 * 512 * 2);
  unsigned short* hall_b = (unsigned short*)alloc((size_t)1408 * 512 * 2);
  float* ge = (float*)alloc((size_t)1408 * 2048 * 4);
  float* hc = (float*)alloc((size_t)64 * 1024 * 4);
  unsigned short* xcat = (unsigned short*)alloc((size_t)64 * 3072 * 2);

  k_prep<<<1, 64, 0, stream>>>(cap_len, captions, sind, dlen, emb_rows, out_caps, out_dlen, out_sind);
  hipMemsetAsync(out_alph, 0, (size_t)263424 * 4, stream);
  hipMemsetAsync(flags, 0, 256 * 32 * 4, stream);
  hipMemsetAsync(gen, 0, 256, stream);
  hipMemsetAsync(meanb + (size_t)64 * 2048, 0, (size_t)64 * 2048 * 2, stream);

  k_gather_enc<<<12544, 256, 0, stream>>>(enc, sind, enc_b, enc8);
  k_conv8<<<128, 256, 0, stream>>>(Wd_att, Wd8, 32768, 1024.f);
  k_tc<<<dim3(8, 32), 256, 0, stream>>>(We_att, WeattT, 2048, 512, 2048, 0, 0);
  k_tc<<<dim3(32, 8), 256, 0, stream>>>(W_ih, WihemT, 512, 2048, 512, 0, 0);
  k_tc<<<dim3(32, 32), 256, 0, stream>>>(W_ih + (size_t)512 * 2048, Wcat, 2048, 2048, 2560, 0, 1);
  k_tc<<<dim3(32, 8), 256, 0, stream>>>(W_hh, Wcat, 512, 2048, 2560, 2048, 1);
  k_tc<<<dim3(500, 8), 256, 0, stream>>>(W_fc, WfcT, 512, 32000, 512, 0, 0);
  k_tc<<<dim3(8, 32), 256, 0, stream>>>(W_init_h, WinitT, 2048, 512, 2048, 0, 0);
  k_tc<<<dim3(8, 32), 256, 0, stream>>>(W_init_c, WinitT + (size_t)512 * 2048, 2048, 512, 2048, 0, 0);
  k_biascat<<<4, 256, 0, stream>>>(b_init_h, b_init_c, binit);
  k_gather_emb<<<1408, 256, 0, stream>>>(emb, emb_rows, Aemb_b);
  k_meanb<<<dim3(64, 8), 256, 0, stream>>>(enc_b, meanb);

  // h0/c0: mean @ WinitT^T -> hc (M=128 pad, N=1024, K=2048)
  k_gemm<<<dim3(1, 8), 256, 0, stream>>>(meanb, WinitT, binit, nullptr, hc, nullptr, nullptr,
                                         128, 1024, 2048, 0, 64);
  k_h0b<<<128, 256, 0, stream>>>(hc, xcat);
  // pre_att = enc_s @ We_att + be_att -> bf16
  k_gemm<<<dim3(98, 4), 256, 0, stream>>>(enc_b, WeattT, be_att, nullptr, nullptr, preatt_b,
                                          nullptr, 12544, 512, 2048, 1, 12544);
  // ge = emb_seq @ W_ih[0:512] + b_ih + b_hh -> f32
  k_gemm<<<dim3(11, 16), 256, 0, stream>>>(Aemb_b, WihemT, b_ih, b_hh, ge, nullptr, nullptr,
                                           1408, 2048, 512, 0, 1344);
  // the 21-step recurrence
  k_loop<<<256, 256, 0, stream>>>(preatt_b, enc8, Wd8, bd_att, v_att, W_beta, b_beta, Wcat,
                                  ge, dlen, hc, xcat, hall_b, flags, gen);
  // predictions = mask(h_all @ W_fc + b_fc) permuted to [b][t][v]
  k_gemm<<<dim3(11, 250), 256, 0, stream>>>(hall_b, WfcT, b_fc, nullptr, out_pred, nullptr,
                                            dlen, 1408, 32000, 512, 2, 1344);
}

// Round 6
// 2220.283 us; speedup vs baseline: 2.1367x; 1.3122x over previous
//
#include <hip/hip_runtime.h>

typedef __attribute__((ext_vector_type(8))) short short8;
typedef __attribute__((ext_vector_type(4))) float f32x4;

#define DEV static __device__ __forceinline__

DEV unsigned short f2bf(float x) {
  unsigned u = __float_as_uint(x);
  return (unsigned short)((u + 0x7fffu + ((u >> 16) & 1u)) >> 16);
}
DEV float bf2f(unsigned short h) { return __uint_as_float(((unsigned)h) << 16); }
DEV unsigned char q8(float x, float s) {
  float y = fminf(fmaxf(x * s, -127.f), 127.f);
  return (unsigned char)(((int)rintf(y)) & 0xff);
}
DEV unsigned nib4(float x) {
  float y = fminf(fmaxf(x * 2.f, -7.f), 7.f);
  return ((unsigned)(int)rintf(y)) & 0xFu;
}

#if __has_builtin(__builtin_amdgcn_sdot4)
#define SDOT4(a, b, c) __builtin_amdgcn_sdot4((int)(a), (int)(b), (c), false)
#else
DEV int SDOT4(unsigned a, unsigned b, int c) {
#pragma unroll
  for (int j = 0; j < 4; ++j)
    c += ((int)(a << (24 - 8 * j)) >> 24) * ((int)(b << (24 - 8 * j)) >> 24);
  return c;
}
#endif

// agent-scope relaxed atomics: coherent via IF$ (bypass non-coherent L2 copies)
DEV float ald_f(const float* p) {
  return __hip_atomic_load(p, __ATOMIC_RELAXED, __HIP_MEMORY_SCOPE_AGENT);
}
DEV void ast_f(float* p, float v) {
  __hip_atomic_store(p, v, __ATOMIC_RELAXED, __HIP_MEMORY_SCOPE_AGENT);
}
DEV void ast_u(unsigned* p, unsigned v) {
  __hip_atomic_store(p, v, __ATOMIC_RELAXED, __HIP_MEMORY_SCOPE_AGENT);
}
DEV unsigned long long ald_u64(const unsigned long long* p) {
  return __hip_atomic_load(p, __ATOMIC_RELAXED, __HIP_MEMORY_SCOPE_AGENT);
}
union U16 { unsigned long long q[2]; short8 s; };

// ---------------- prep: stable descending argsort + int outputs ----------------
__global__ void k_prep(const int* __restrict__ cap_len, const int* __restrict__ captions,
                       int* __restrict__ sind, int* __restrict__ dlen, int* __restrict__ emb_rows,
                       float* __restrict__ out_caps, float* __restrict__ out_dlen,
                       float* __restrict__ out_sind) {
  __shared__ int lens[64];
  __shared__ int ssind[64];
  int i = threadIdx.x;
  lens[i] = cap_len[i];
  __syncthreads();
  int li = lens[i];
  int rank = 0;
  for (int j = 0; j < 64; ++j) {
    int lj = lens[j];
    rank += (lj > li || (lj == li && j < i)) ? 1 : 0;
  }
  ssind[rank] = i;
  __syncthreads();
  int b = i;
  int s = ssind[b];
  sind[b] = s;
  int dl = lens[s] - 1;
  dlen[b] = dl;
  out_dlen[b] = (float)dl;
  out_sind[b] = (float)s;
  for (int l = 0; l < 22; ++l) {
    int cv = captions[s * 22 + l];
    out_caps[b * 22 + l] = (float)cv;
    if (l < 21) emb_rows[l * 64 + b] = cv;
  }
}

// ---------------- gather sorted encoder rows -> bf16 + int4(scale 2) ----------------
__global__ __launch_bounds__(256) void k_gather_enc(const float* __restrict__ enc,
                                                    const int* __restrict__ sind,
                                                    unsigned short* __restrict__ dst,
                                                    unsigned char* __restrict__ dst4) {
  int bp = blockIdx.x;  // 0..12543
  int b = bp / 196, p = bp % 196;
  int tx = threadIdx.x;
  const float* src = enc + ((size_t)sind[b] * 196 + p) * 2048 + tx * 8;
  float4 v0 = *(const float4*)src;
  float4 v1 = *(const float4*)(src + 4);
  uint4 o;
  o.x = f2bf(v0.x) | ((unsigned)f2bf(v0.y) << 16);
  o.y = f2bf(v0.z) | ((unsigned)f2bf(v0.w) << 16);
  o.z = f2bf(v1.x) | ((unsigned)f2bf(v1.y) << 16);
  o.w = f2bf(v1.z) | ((unsigned)f2bf(v1.w) << 16);
  *(uint4*)(dst + (size_t)bp * 2048 + tx * 8) = o;
  // int4 slice layout: [(b*4+q)][196][256B]  (quarter q = channels [q*512, q*512+512))
  int q = tx >> 6, lc = (tx & 63) * 4;
  unsigned u = nib4(v0.x) | (nib4(v0.y) << 4) | (nib4(v0.z) << 8) | (nib4(v0.w) << 12) |
               (nib4(v1.x) << 16) | (nib4(v1.y) << 20) | (nib4(v1.z) << 24) | (nib4(v1.w) << 28);
  *(unsigned*)(dst4 + ((size_t)(b * 4 + q) * 196 + p) * 256 + lc) = u;
}

// ---- transpose-convert: src f32 [Ks][N] -> dst bf16 rows perm(n), stride/off ----
__global__ __launch_bounds__(256) void k_tc(const float* __restrict__ src,
                                            unsigned short* __restrict__ dst, int Ks, int N,
                                            int dstStride, int dstOff, int perm) {
  __shared__ float tile[64][65];
  int n0 = blockIdx.x * 64, k0 = blockIdx.y * 64;
  int tx = threadIdx.x & 63, ty = threadIdx.x >> 6;
#pragma unroll
  for (int r = 0; r < 16; ++r) {
    int kr = r * 4 + ty;
    tile[kr][tx] = src[(size_t)(k0 + kr) * N + n0 + tx];
  }
  __syncthreads();
#pragma unroll
  for (int r = 0; r < 16; ++r) {
    int nr = r * 4 + ty;
    int n = n0 + nr;
    int prow = perm ? (((n >> 3) & 63) * 32 + (n >> 9) * 8 + (n & 7)) : n;
    dst[(size_t)prow * dstStride + dstOff + k0 + tx] = f2bf(tile[tx][nr]);
  }
}

// ---- transpose-convert to int8: src f32 [Ks][N] -> dst int8 [N][Ks] ----
__global__ __launch_bounds__(256) void k_tc8(const float* __restrict__ src,
                                             unsigned char* __restrict__ dst, int Ks, int N,
                                             float scale) {
  __shared__ float tile[64][65];
  int n0 = blockIdx.x * 64, k0 = blockIdx.y * 64;
  int tx = threadIdx.x & 63, ty = threadIdx.x >> 6;
#pragma unroll
  for (int r = 0; r < 16; ++r) {
    int kr = r * 4 + ty;
    tile[kr][tx] = src[(size_t)(k0 + kr) * N + n0 + tx];
  }
  __syncthreads();
#pragma unroll
  for (int r = 0; r < 16; ++r) {
    int nr = r * 4 + ty;
    dst[(size_t)(n0 + nr) * Ks + k0 + tx] = q8(tile[tx][nr], scale);
  }
}

// ---------------- gather embedding rows -> bf16 A [1408][512] (zero pad) ----------------
__global__ __launch_bounds__(256) void k_gather_emb(const float* __restrict__ emb,
                                                    const int* __restrict__ rows,
                                                    unsigned short* __restrict__ dst) {
  int r = blockIdx.x;
  unsigned short* d = dst + (size_t)r * 512;
  int t = threadIdx.x;
  if (r >= 1344) { d[t] = 0; d[t + 256] = 0; return; }
  const float* s = emb + (size_t)rows[r] * 512;
  d[t] = f2bf(s[t]);
  d[t + 256] = f2bf(s[t + 256]);
}

// ---------------- mean over 196 pixels (from sorted bf16 enc) -> bf16 ----------------
__global__ __launch_bounds__(256) void k_meanb(const unsigned short* __restrict__ encb,
                                               unsigned short* __restrict__ meanb) {
  int b = blockIdx.x, e = blockIdx.y * 256 + threadIdx.x;
  const unsigned short* base = encb + (size_t)b * 196 * 2048 + e;
  float s = 0.f;
  for (int p = 0; p < 196; ++p) s += bf2f(base[(size_t)p * 2048]);
  meanb[(size_t)b * 2048 + e] = f2bf(s * (1.0f / 196.0f));
}

__global__ void k_biascat(const float* __restrict__ bh, const float* __restrict__ bc,
                          float* __restrict__ dst) {
  int i = blockIdx.x * 256 + threadIdx.x;  // grid 4
  dst[i] = (i < 512) ? bh[i] : bc[i - 512];
}

// h0 f32 -> xcat h-section 0 (bf16)
__global__ void k_h0b(const float* __restrict__ hc, unsigned short* __restrict__ xcat) {
  int i = blockIdx.x * 256 + threadIdx.x;  // 32768
  int b = i >> 9, j = i & 511;
  xcat[(size_t)b * 3072 + 2048 + j] = f2bf(hc[b * 1024 + j]);
}

// ---------------- MFMA GEMM: C[M][N] = A[M][K] @ Bt[N][K]^T (+bias) ----------------
// mode 0: f32 out. mode 1: bf16 out. mode 2: FC epilogue. mode 3: int8 out (scale 32).
__global__ __launch_bounds__(256) void k_gemm(const unsigned short* __restrict__ A,
                                              const unsigned short* __restrict__ Bt,
                                              const float* __restrict__ bias1,
                                              const float* __restrict__ bias2,
                                              float* __restrict__ Cf,
                                              unsigned short* __restrict__ Cb,
                                              const int* __restrict__ dlen,
                                              int M, int N, int K, int mode, int Mreal) {
  __shared__ unsigned short As[128 * 64];
  __shared__ unsigned short Bs[128 * 64];
  int t = threadIdx.x;
  int lane = t & 63, w = t >> 6;
  int wm = w >> 1, wn = w & 1;
  int m0 = blockIdx.x * 128, n0 = blockIdx.y * 128;
  f32x4 acc[4][4] = {};
  uint4 ra[4], rb[4];

#define LOADREGS(kc)                                                             \
  {                                                                              \
    _Pragma("unroll") for (int r = 0; r < 4; ++r) {                              \
      int idx = r * 256 + t;                                                     \
      int row = idx >> 3, ke = (idx & 7) * 8;                                    \
      ra[r] = *(const uint4*)(A + (size_t)(m0 + row) * K + (kc) + ke);           \
      rb[r] = *(const uint4*)(Bt + (size_t)(n0 + row) * K + (kc) + ke);          \
    }                                                                            \
  }

  LOADREGS(0);
  for (int kc = 0; kc < K; kc += 64) {
    __syncthreads();
#pragma unroll
    for (int r = 0; r < 4; ++r) {
      int idx = r * 256 + t;
      int row = idx >> 3, cb = (idx & 7) * 16;
      int sw = cb ^ ((row & 7) << 4);
      *(uint4*)((char*)As + row * 128 + sw) = ra[r];
      *(uint4*)((char*)Bs + row * 128 + sw) = rb[r];
    }
    __syncthreads();
    if (kc + 64 < K) LOADREGS(kc + 64);
#pragma unroll
    for (int ks = 0; ks < 2; ++ks) {
      short8 af[4], bf[4];
#pragma unroll
      for (int mi = 0; mi < 4; ++mi) {
        int row = wm * 64 + mi * 16 + (lane & 15);
        int kb = (ks * 64 + (lane >> 4) * 16) ^ ((row & 7) << 4);
        af[mi] = *(const short8*)((const char*)As + row * 128 + kb);
      }
#pragma unroll
      for (int ni = 0; ni < 4; ++ni) {
        int row = wn * 64 + ni * 16 + (lane & 15);
        int kb = (ks * 64 + (lane >> 4) * 16) ^ ((row & 7) << 4);
        bf[ni] = *(const short8*)((const char*)Bs + row * 128 + kb);
      }
#pragma unroll
      for (int mi = 0; mi < 4; ++mi)
#pragma unroll
        for (int ni = 0; ni < 4; ++ni)
          acc[mi][ni] = __builtin_amdgcn_mfma_f32_16x16x32_bf16(af[mi], bf[ni], acc[mi][ni], 0, 0, 0);
    }
  }
  int rbase = (lane >> 4) * 4;
#pragma unroll
  for (int mi = 0; mi < 4; ++mi) {
#pragma unroll
    for (int ni = 0; ni < 4; ++ni) {
      int n = n0 + wn * 64 + ni * 16 + (lane & 15);
      float badd = (bias1 ? bias1[n] : 0.f) + (bias2 ? bias2[n] : 0.f);
#pragma unroll
      for (int r = 0; r < 4; ++r) {
        int m = m0 + wm * 64 + mi * 16 + rbase + r;
        if (m >= Mreal) continue;
        float v = acc[mi][ni][r] + badd;
        if (mode == 0) {
          Cf[(size_t)m * N + n] = v;
        } else if (mode == 1) {
          Cb[(size_t)m * N + n] = f2bf(v);
        } else if (mode == 3) {
          ((unsigned char*)Cb)[(size_t)m * N + n] = q8(v, 32.f);
        } else {
          int tt = m >> 6, bb = m & 63;
          Cf[(size_t)bb * 672000 + (size_t)tt * 32000 + n] = (tt < dlen[bb]) ? v : 0.f;
        }
      }
    }
  }
#undef LOADREGS
}

// ------------- fence-free grid barrier: per-block flags + master broadcast -------------
DEV void gbar(unsigned* flags, unsigned* gen, unsigned target) {
  __syncthreads();
  if (threadIdx.x == 0)
    __hip_atomic_store(&flags[blockIdx.x * 32], target, __ATOMIC_RELAXED,
                       __HIP_MEMORY_SCOPE_AGENT);
  if (blockIdx.x == 0) {
    while (__hip_atomic_load(&flags[threadIdx.x * 32], __ATOMIC_RELAXED,
                             __HIP_MEMORY_SCOPE_AGENT) < target)
      __builtin_amdgcn_s_sleep(1);
    __syncthreads();
    if (threadIdx.x == 0)
      __hip_atomic_store(gen, target, __ATOMIC_RELAXED, __HIP_MEMORY_SCOPE_AGENT);
  }
  if (threadIdx.x == 0) {
    while (__hip_atomic_load(gen, __ATOMIC_RELAXED, __HIP_MEMORY_SCOPE_AGENT) < target)
      __builtin_amdgcn_s_sleep(1);
  }
  __syncthreads();
}

// ---------------- persistent 21-step decoder loop ----------------
__global__ __launch_bounds__(256, 1) void k_loop(
    const unsigned char* __restrict__ preatt8, const unsigned char* __restrict__ enc4,
    const unsigned char* __restrict__ WdT8, const float* __restrict__ bd,
    const float* __restrict__ v_att, const float* __restrict__ Wbeta,
    const float* __restrict__ bbeta, const unsigned short* __restrict__ Wcat,
    const float* __restrict__ ge, const int* __restrict__ dlen, float* __restrict__ hc,
    unsigned short* __restrict__ xcat, unsigned short* __restrict__ hall,
    unsigned* flags, unsigned* gen) {
  __shared__ __align__(16) unsigned char encL[50176];     // [196][256B] int4 channel-quarter
  __shared__ __align__(16) unsigned char preattL[100352]; // [196][512] int8 (scale 32)
  __shared__ float rvP[512];                              // v_att / 32
  __shared__ int dlP[64];
  __shared__ __align__(16) union Scr {
    struct {
      float eld[200];
      union {
        struct {
          float hld[512];
          float rd[512];  // 32 * datt
          float red[256];
          float gpart[4];
          unsigned hq[128];  // h int8 (scale 32) packed
        } s;
        float lred[4][512];
      } u;
    } a;
    struct { float pd[2][64][17]; } p3;
  } scr;
  int blk = blockIdx.x;
  int t = threadIdx.x;
  int lane = t & 63, w = t >> 6;
  int b = blk >> 2, q = blk & 3;
  unsigned target = 0;

  // prologue: pin enc int4 slice + preatt int8 slice in LDS
  {
    const uint4* s4 = (const uint4*)(enc4 + (size_t)blk * 50176);
    uint4* d4 = (uint4*)encL;
    for (int i = t; i < 3136; i += 256) d4[i] = s4[i];
    const uint4* sp = (const uint4*)(preatt8 + (size_t)b * 100352);
    uint4* dp = (uint4*)preattL;
    for (int i = t; i < 6272; i += 256) dp[i] = sp[i];
    rvP[t] = v_att[t] * (1.f / 32.f);
    rvP[t + 256] = v_att[t + 256] * (1.f / 32.f);
    if (t < 64) dlP[t] = dlen[t];
    __syncthreads();
  }

  for (int s = 0; s < 21; ++s) {
    // ======== Phase A: datt + e(196) + softmax + gate + z-quarter ========
    {
      float h0 = ald_f(&hc[b * 1024 + t]);
      float h1 = ald_f(&hc[b * 1024 + 256 + t]);
      scr.a.u.s.hld[t] = h0;
      scr.a.u.s.hld[t + 256] = h1;
      float gp = h0 * Wbeta[t] + h1 * Wbeta[t + 256];
#pragma unroll
      for (int off = 32; off > 0; off >>= 1) gp += __shfl_xor(gp, off, 64);
      if (lane == 0) scr.a.u.s.gpart[w] = gp;
      __syncthreads();
      // pack h int8 (scale 32)
      if (t < 128) {
        unsigned u0 = (unsigned)q8(scr.a.u.s.hld[t * 4], 32.f) |
                      ((unsigned)q8(scr.a.u.s.hld[t * 4 + 1], 32.f) << 8) |
                      ((unsigned)q8(scr.a.u.s.hld[t * 4 + 2], 32.f) << 16) |
                      ((unsigned)q8(scr.a.u.s.hld[t * 4 + 3], 32.f) << 24);
        scr.a.u.s.hq[t] = u0;
      }
      __syncthreads();
      // datt via int8 dot: lane covers cols c0, c0+1; rd = 32*datt
      {
        int c0 = w * 128 + lane * 2;
        int acc0 = 0, acc1 = 0;
        const uint4* wp0 = (const uint4*)(WdT8 + (size_t)c0 * 512);
        const uint4* wp1 = wp0 + 32;
        const uint4* hp = (const uint4*)scr.a.u.s.hq;
#pragma unroll 4
        for (int i = 0; i < 32; ++i) {
          uint4 hv = hp[i];
          uint4 a0 = wp0[i], a1 = wp1[i];
          acc0 = SDOT4(a0.x, hv.x, acc0);
          acc0 = SDOT4(a0.y, hv.y, acc0);
          acc0 = SDOT4(a0.z, hv.z, acc0);
          acc0 = SDOT4(a0.w, hv.w, acc0);
          acc1 = SDOT4(a1.x, hv.x, acc1);
          acc1 = SDOT4(a1.y, hv.y, acc1);
          acc1 = SDOT4(a1.z, hv.z, acc1);
          acc1 = SDOT4(a1.w, hv.w, acc1);
        }
        // true datt = acc/(32*2048); rd = 32*datt = acc/2048 + 32*bd
        scr.a.u.s.rd[c0] = 32.f * bd[c0] + (float)acc0 * (1.f / 2048.f);
        scr.a.u.s.rd[c0 + 1] = 32.f * bd[c0 + 1] + (float)acc1 * (1.f / 2048.f);
      }
      __syncthreads();
      // e for all 196 pixels from LDS preatt int8: 32 groups of 8 lanes
      int g = t & 7, grp = t >> 3;
#pragma unroll
      for (int r = 0; r < 7; ++r) {
        int p = r * 32 + grp;
        float acc = 0.f;
        if (p < 196) {
          const unsigned char* pp = preattL + p * 512;
#pragma unroll
          for (int i = 0; i < 8; ++i) {
            int c0 = i * 64 + g * 8;
            uint2 pv = *(const uint2*)(pp + c0);
#pragma unroll
            for (int jj = 0; jj < 4; ++jj) {
              float x0 = (float)((int)(pv.x << (24 - 8 * jj)) >> 24) + scr.a.u.s.rd[c0 + jj];
              float x1 = (float)((int)(pv.y << (24 - 8 * jj)) >> 24) + scr.a.u.s.rd[c0 + 4 + jj];
              acc += fmaxf(x0, 0.f) * rvP[c0 + jj];
              acc += fmaxf(x1, 0.f) * rvP[c0 + 4 + jj];
            }
          }
        }
        acc += __shfl_xor(acc, 1, 64);
        acc += __shfl_xor(acc, 2, 64);
        acc += __shfl_xor(acc, 4, 64);
        if (g == 0 && p < 196) scr.a.eld[p] = acc;
      }
      __syncthreads();
      // softmax + gate fold (block-local)
      float gate = scr.a.u.s.gpart[0] + scr.a.u.s.gpart[1] + scr.a.u.s.gpart[2] +
                   scr.a.u.s.gpart[3] + bbeta[0];
      scr.a.u.s.red[t] = (t < 196) ? scr.a.eld[t] : -3.4e38f;
      __syncthreads();
      for (int st = 128; st > 0; st >>= 1) {
        if (t < st) scr.a.u.s.red[t] = fmaxf(scr.a.u.s.red[t], scr.a.u.s.red[t + st]);
        __syncthreads();
      }
      float mx = scr.a.u.s.red[0];
      __syncthreads();
      float ex = (t < 196) ? expf(scr.a.eld[t] - mx) : 0.f;
      scr.a.u.s.red[t] = ex;
      __syncthreads();
      for (int st = 128; st > 0; st >>= 1) {
        if (t < st) scr.a.u.s.red[t] += scr.a.u.s.red[t + st];
        __syncthreads();
      }
      float inv = gate / scr.a.u.s.red[0];
      __syncthreads();
      if (t < 196) scr.a.eld[t] = ex * inv;  // alpha*gate
      __syncthreads();
      // z: wave w pixels [w*49,+49) from LDS int4 enc (lred overlays hld/rd/red)
      {
        float a[8] = {0, 0, 0, 0, 0, 0, 0, 0};
        const unsigned char* base = encL + (size_t)(w * 49) * 256 + lane * 4;
#pragma unroll 7
        for (int it = 0; it < 49; ++it) {
          unsigned v = *(const unsigned*)(base + (size_t)it * 256);
          float al = scr.a.eld[w * 49 + it];
#pragma unroll
          for (int j = 0; j < 4; ++j) {
            float lo = (float)((int)(v << (28 - 8 * j)) >> 28);
            float hi = (float)((int)(v << (24 - 8 * j)) >> 28);
            a[2 * j] += al * lo;
            a[2 * j + 1] += al * hi;
          }
        }
#pragma unroll
        for (int i = 0; i < 8; ++i) scr.a.u.lred[w][lane * 8 + i] = a[i];
      }
      __syncthreads();
      {
        int j = t * 2;
        float z0 = (scr.a.u.lred[0][j] + scr.a.u.lred[1][j] + scr.a.u.lred[2][j] +
                    scr.a.u.lred[3][j]) * 0.5f;
        float z1 = (scr.a.u.lred[0][j + 1] + scr.a.u.lred[1][j + 1] + scr.a.u.lred[2][j + 1] +
                    scr.a.u.lred[3][j + 1]) * 0.5f;
        ast_u((unsigned*)(xcat + (size_t)b * 3072 + q * 512 + j),
              (unsigned)f2bf(z0) | ((unsigned)f2bf(z1) << 16));
      }
    }
    gbar(flags, gen, ++target);

    // ======== Phase B: gates MFMA + LSTM cell (blocks 0..63) ========
    if (blk < 64) {
      int c = blk;
      int par = s & 1;
      int P = w >> 1, kh = w & 1;
      f32x4 acc[4] = {};
      int mrow = lane & 15;
      int krow = (lane >> 4) * 8;
      const unsigned short* wrow = Wcat + (size_t)(c * 32 + P * 16 + (lane & 15)) * 2560;
#pragma unroll 4
      for (int kk = 0; kk < 40; ++kk) {
        int k = kh * 1280 + kk * 32 + krow;
        size_t koff = (size_t)k + ((k >= 2048 && par) ? 512 : 0);
        short8 a[4], bfr;
#pragma unroll
        for (int mi = 0; mi < 4; ++mi) {
          const unsigned long long* xq =
              (const unsigned long long*)(xcat + (size_t)(mi * 16 + mrow) * 3072 + koff);
          U16 u;
          u.q[0] = ald_u64(xq);
          u.q[1] = ald_u64(xq + 1);
          a[mi] = u.s;
        }
        bfr = *(const short8*)(wrow + k);  // Wcat L2-warm
#pragma unroll
        for (int mi = 0; mi < 4; ++mi)
          acc[mi] = __builtin_amdgcn_mfma_f32_16x16x32_bf16(a[mi], bfr, acc[mi], 0, 0, 0);
      }
      int mbase = (lane >> 4) * 4;
      if (kh) {
#pragma unroll
        for (int mi = 0; mi < 4; ++mi)
#pragma unroll
          for (int r = 0; r < 4; ++r)
            scr.p3.pd[P][mi * 16 + mbase + r][lane & 15] = acc[mi][r];
      }
      __syncthreads();
      if (!kh) {
#pragma unroll
        for (int mi = 0; mi < 4; ++mi)
#pragma unroll
          for (int r = 0; r < 4; ++r)
            scr.p3.pd[P][mi * 16 + mbase + r][lane & 15] += acc[mi][r];
      }
      __syncthreads();
      {
        int b2 = t & 63;
        int jl0 = (t >> 6) * 2;
        unsigned hallp = 0, hxp = 0;
#pragma unroll
        for (int u = 0; u < 2; ++u) {
          int jl = jl0 + u;
          float sg[4];
#pragma unroll
          for (int gq = 0; gq < 4; ++gq) {
            int bc = gq * 8 + jl;
            sg[gq] = scr.p3.pd[bc >> 4][b2][bc & 15];
          }
          int jg = c * 8 + jl;
          const float* gep = ge + ((size_t)(s * 64 + b2)) * 2048;
          float gi = sg[0] + gep[jg];
          float gf = sg[1] + gep[512 + jg];
          float gg = sg[2] + gep[1024 + jg];
          float go = sg[3] + gep[1536 + jg];
          float si = 1.f / (1.f + expf(-gi));
          float sf = 1.f / (1.f + expf(-gf));
          float so = 1.f / (1.f + expf(-go));
          float cold = ald_f(&hc[b2 * 1024 + 512 + jg]);
          float cn = sf * cold + si * tanhf(gg);
          float hn = so * tanhf(cn);
          bool msk = s < dlP[b2];
          float hold = ald_f(&hc[b2 * 1024 + jg]);
          float hnew = msk ? hn : hold;
          float cnew = msk ? cn : cold;
          ast_f(&hc[b2 * 1024 + jg], hnew);
          ast_f(&hc[b2 * 1024 + 512 + jg], cnew);
          hallp |= ((unsigned)f2bf(hn)) << (u * 16);
          hxp |= ((unsigned)f2bf(hnew)) << (u * 16);
        }
        int jg0 = c * 8 + jl0;
        ast_u((unsigned*)(xcat + (size_t)b2 * 3072 + 2048 + (par ^ 1) * 512 + jg0), hxp);
        ast_u((unsigned*)(hall + ((size_t)s * 64 + b2) * 512 + jg0), hallp);
      }
    }
    gbar(flags, gen, ++target);
  }
}

extern "C" void kernel_launch(void* const* d_in, const int* in_sizes, int n_in,
                              void* d_out, int out_size, void* d_ws, size_t ws_size,
                              hipStream_t stream) {
  (void)in_sizes; (void)n_in; (void)out_size; (void)ws_size;
  const float* enc = (const float*)d_in[0];
  const int* captions = (const int*)d_in[1];
  const int* cap_len = (const int*)d_in[2];
  const float* emb = (const float*)d_in[3];
  const float* We_att = (const float*)d_in[4];
  const float* be_att = (const float*)d_in[5];
  const float* Wd_att = (const float*)d_in[6];
  const float* bd_att = (const float*)d_in[7];
  const float* v_att = (const float*)d_in[8];
  const float* W_beta = (const float*)d_in[10];
  const float* b_beta = (const float*)d_in[11];
  const float* W_ih = (const float*)d_in[12];
  const float* b_ih = (const float*)d_in[13];
  const float* W_hh = (const float*)d_in[14];
  const float* b_hh = (const float*)d_in[15];
  const float* W_init_h = (const float*)d_in[16];
  const float* b_init_h = (const float*)d_in[17];
  const float* W_init_c = (const float*)d_in[18];
  const float* b_init_c = (const float*)d_in[19];
  const float* W_fc = (const float*)d_in[20];
  const float* b_fc = (const float*)d_in[21];

  float* out = (float*)d_out;
  float* out_pred = out;             // 64*21*32000
  float* out_caps = out + 43008000;  // 1408
  float* out_dlen = out + 43009408;  // 64
  float* out_alph = out + 43009472;  // 263424
  float* out_sind = out + 43272896;  // 64

  char* ws = (char*)d_ws;
  size_t off = 0;
  auto alloc = [&](size_t bytes) -> void* {
    off = (off + 255) & ~(size_t)255;
    void* p = ws + off;
    off += bytes;
    return p;
  };
  int* sind = (int*)alloc(64 * 4);
  int* dlen = (int*)alloc(64 * 4);
  int* emb_rows = (int*)alloc(1344 * 4);
  unsigned* flags = (unsigned*)alloc(256 * 32 * 4);
  unsigned* gen = (unsigned*)alloc(256);
  unsigned short* enc_b = (unsigned short*)alloc((size_t)25690112 * 2);
  unsigned char* enc4 = (unsigned char*)alloc((size_t)64 * 4 * 196 * 256);
  unsigned char* preatt8 = (unsigned char*)alloc((size_t)12544 * 512);
  unsigned short* WeattT = (unsigned short*)alloc((size_t)512 * 2048 * 2);
  unsigned short* WihemT = (unsigned short*)alloc((size_t)2048 * 512 * 2);
  unsigned short* Wcat = (unsigned short*)alloc((size_t)2048 * 2560 * 2);
  unsigned short* WfcT = (unsigned short*)alloc((size_t)32000 * 512 * 2);
  unsigned short* WinitT = (unsigned short*)alloc((size_t)1024 * 2048 * 2);
  unsigned char* WdT8 = (unsigned char*)alloc((size_t)512 * 512);
  unsigned short* meanb = (unsigned short*)alloc((size_t)128 * 2048 * 2);
  float* binit = (float*)alloc(1024 * 4);
  unsigned short* Aemb_b = (unsigned short*)alloc((size_t)1408 * 512 * 2);
  unsigned short* hall_b = (unsigned short*)alloc((size_t)1408 * 512 * 2);
  float* ge = (float*)alloc((size_t)1408 * 2048 * 4);
  float* hc = (float*)alloc((size_t)64 * 1024 * 4);
  unsigned short* xcat = (unsigned short*)alloc((size_t)64 * 3072 * 2);

  k_prep<<<1, 64, 0, stream>>>(cap_len, captions, sind, dlen, emb_rows, out_caps, out_dlen, out_sind);
  hipMemsetAsync(out_alph, 0, (size_t)263424 * 4, stream);
  hipMemsetAsync(flags, 0, 256 * 32 * 4, stream);
  hipMemsetAsync(gen, 0, 256, stream);
  hipMemsetAsync(meanb + (size_t)64 * 2048, 0, (size_t)64 * 2048 * 2, stream);

  k_gather_enc<<<12544, 256, 0, stream>>>(enc, sind, enc_b, enc4);
  k_tc8<<<dim3(8, 8), 256, 0, stream>>>(Wd_att, WdT8, 512, 512, 2048.f);
  k_tc<<<dim3(8, 32), 256, 0, stream>>>(We_att, WeattT, 2048, 512, 2048, 0, 0);
  k_tc<<<dim3(32, 8), 256, 0, stream>>>(W_ih, WihemT, 512, 2048, 512, 0, 0);
  k_tc<<<dim3(32, 32), 256, 0, stream>>>(W_ih + (size_t)512 * 2048, Wcat, 2048, 2048, 2560, 0, 1);
  k_tc<<<dim3(32, 8), 256, 0, stream>>>(W_hh, Wcat, 512, 2048, 2560, 2048, 1);
  k_tc<<<dim3(500, 8), 256, 0, stream>>>(W_fc, WfcT, 512, 32000, 512, 0, 0);
  k_tc<<<dim3(8, 32), 256, 0, stream>>>(W_init_h, WinitT, 2048, 512, 2048, 0, 0);
  k_tc<<<dim3(8, 32), 256, 0, stream>>>(W_init_c, WinitT + (size_t)512 * 2048, 2048, 512, 2048, 0, 0);
  k_biascat<<<4, 256, 0, stream>>>(b_init_h, b_init_c, binit);
  k_gather_emb<<<1408, 256, 0, stream>>>(emb, emb_rows, Aemb_b);
  k_meanb<<<dim3(64, 8), 256, 0, stream>>>(enc_b, meanb);

  // h0/c0: mean @ WinitT^T -> hc (M=128 pad, N=1024, K=2048)
  k_gemm<<<dim3(1, 8), 256, 0, stream>>>(meanb, WinitT, binit, nullptr, hc, nullptr, nullptr,
                                         128, 1024, 2048, 0, 64);
  k_h0b<<<128, 256, 0, stream>>>(hc, xcat);
  // pre_att = enc_s @ We_att + be_att -> int8 (scale 32)
  k_gemm<<<dim3(98, 4), 256, 0, stream>>>(enc_b, WeattT, be_att, nullptr, nullptr,
                                          (unsigned short*)preatt8, nullptr, 12544, 512, 2048, 3,
                                          12544);
  // ge = emb_seq @ W_ih[0:512] + b_ih + b_hh -> f32
  k_gemm<<<dim3(11, 16), 256, 0, stream>>>(Aemb_b, WihemT, b_ih, b_hh, ge, nullptr, nullptr,
                                           1408, 2048, 512, 0, 1344);
  // the 21-step recurrence
  k_loop<<<256, 256, 0, stream>>>(preatt8, enc4, WdT8, bd_att, v_att, W_beta, b_beta, Wcat,
                                  ge, dlen, hc, xcat, hall_b, flags, gen);
  // predictions = mask(h_all @ W_fc + b_fc) permuted to [b][t][v]
  k_gemm<<<dim3(11, 250), 256, 0, stream>>>(hall_b, WfcT, b_fc, nullptr, out_pred, nullptr,
                                            dlen, 1408, 32000, 512, 2, 1344);
}